// Round 8
// baseline (1245.651 us; speedup 1.0000x reference)
//
#include <hip/hip_runtime.h>
#include <hip/hip_bf16.h>
#include <stdint.h>

// Problem constants
#define T_STEPS 128
#define BATCH   2048
#define IN_DIM  18
#define HID     256

// Fragment repack (same layout as R3)
#define NT   48
#define KT0  9
#define KT1  16
#define L0_FRAGS 432
#define L1_FRAGS 768
#define TOT_FRAGS 1200

// d_ws layout (~17.7 MB)
#define CNT_OFF  1310720u
#define CNTA(g)  (CNT_OFF + (uint32_t)(g) * 64u)
#define CNTB(g)  (CNT_OFF + 4096u + (uint32_t)(g) * 64u)
#define CNTC(g)  (CNT_OFF + 8192u + (uint32_t)(g) * 64u)
#define H1_OFF   1441792u
#define H1SLOT(t, g) (H1_OFF + (uint32_t)(((((t) & 3) * 64) + (g)) * 16384))
#define XG_OFF   5898240u
#define XGSLOT(t, g) (XG_OFF + (uint32_t)(((((t) & 3) * 64) + (g)) * 49152))

// xg in-slab layout: col-major 64B rows, XOR-swizzled (kept from R2, passed 3x)
#define XGOFFS(col, inner) ((uint32_t)((col) * 64 + ((inner) ^ (((col) & 7) << 3))))

using frag_ab = __attribute__((ext_vector_type(8))) short;
using f32x4   = __attribute__((ext_vector_type(4))) float;
using uint4v  = __attribute__((ext_vector_type(4))) unsigned int;
using uint2v  = __attribute__((ext_vector_type(2))) unsigned int;

__device__ __forceinline__ unsigned short f2bf(float f) {
  unsigned int u = __float_as_uint(f);
  u = (u + 0x7fffu + ((u >> 16) & 1u)) >> 16;  // RNE
  return (unsigned short)u;
}
__device__ __forceinline__ float bf2f(unsigned short v) {
  return __uint_as_float((uint32_t)v << 16);
}
__device__ __forceinline__ float sigmoidf_(float v) {
  return 1.f / (1.f + __expf(-v));
}
__device__ __forceinline__ float tanhf_(float v) {
  float a = fabsf(v);
  float e = __expf(-2.f * a);
  float r = (1.f - e) / (1.f + e);
  return v < 0.f ? -r : r;
}
__device__ __forceinline__ f32x4 mfma16(frag_ab a, frag_ab b, f32x4 c) {
  return __builtin_amdgcn_mfma_f32_16x16x32_bf16(a, b, c, 0, 0, 0);
}

// ---------------------------------------------------------------------------
// Prologue 1: fp32 weights -> bf16 MFMA B-fragments (layout as R3).
// ---------------------------------------------------------------------------
__global__ __launch_bounds__(256) void repack_w(
    const float* __restrict__ Wih0, const float* __restrict__ Whh0,
    const float* __restrict__ Wih1, const float* __restrict__ Whh1,
    unsigned short* __restrict__ wq)
{
  int g = blockIdx.x * 256 + threadIdx.x;
  if (g >= TOT_FRAGS * 64) return;
  int f = g >> 6;
  int L = g & 63;
  int q = L >> 4, c16 = L & 15;
  unsigned short v[8];
  if (f < L0_FRAGS) {
    int n = f / KT0, kt = f - n * KT0;
    int col = n * 16 + c16;
    if (kt == 0) {
      #pragma unroll
      for (int j = 0; j < 8; ++j) {
        int k = q * 8 + j;
        v[j] = (k < IN_DIM) ? f2bf(Wih0[col * IN_DIM + k]) : (unsigned short)0;
      }
    } else {
      int kb = (kt - 1) * 32 + q * 8;
      #pragma unroll
      for (int j = 0; j < 8; ++j) v[j] = f2bf(Whh0[col * HID + kb + j]);
    }
  } else {
    int f1 = f - L0_FRAGS;
    int n = f1 / KT1, kt = f1 - n * KT1;
    int col = n * 16 + c16;
    const float* __restrict__ W = (kt < 8) ? Wih1 : Whh1;
    int kb = (kt & 7) * 32 + q * 8;
    #pragma unroll
    for (int j = 0; j < 8; ++j) v[j] = f2bf(W[col * HID + kb + j]);
  }
  frag_ab pv;
  #pragma unroll
  for (int j = 0; j < 8; ++j) pv[j] = (short)v[j];
  *(frag_ab*)((char*)wq + ((size_t)f << 10) + (size_t)(L << 4)) = pv;
}

// ---------------------------------------------------------------------------
// Prologue 2: zero the counters (d_ws poisoned each launch).
// ---------------------------------------------------------------------------
__global__ __launch_bounds__(256) void clear_cnt(uint32_t* __restrict__ c) {
  int i = blockIdx.x * 256 + threadIdx.x;
  if (i < 3072) c[i] = 0;
}

// ---------------------------------------------------------------------------
// 3-stage pipeline, PAIR-UNROLLED with R0 register profiles.
// Per pair (2 timesteps): ONE publish + ONE poll-set; counters pair-granular
// (64 pairs; ring 4 t-slots = 2 pair-slots).
//  A: two R0 K-loops back-to-back (mid-pair waits "6" self-retire the carried
//     prefetches), single export of both halves + one drain at pair end.
//  B/C: per HALF, one R0-sized staging set (1 / 3 uint4v) ->
//     [K-loop -> export -> vmcnt(0) -> BARRIER -> LDS store], so every
//     wave's global reads are drained BEFORE the pair-end publish.
//  Register profile per stage == R0 (48 frag VGPRs + <=12 staging), default
//  __launch_bounds__(1024) -- the envelope that compiled correctly 4x.
// Polls: A end-of-tp: CNTB>=tp-1; B end-of-u: CNTA>=u+3 (u<=61), CNTC>=u-1;
//        C end-of-v: CNTB>=v+3 (v<=61). Publish-before-poll everywhere.
// ---------------------------------------------------------------------------
__global__ __launch_bounds__(1024) void gru_pipe(
    const float* __restrict__ x,
    const float* __restrict__ bih0, const float* __restrict__ bhh0,
    const float* __restrict__ bih1, const float* __restrict__ bhh1,
    const float* __restrict__ fcw,  const float* __restrict__ fcb,
    char* __restrict__ ws,
    float* __restrict__ out)
{
  __shared__ __align__(16) char smem[132096];  // C: xg0(48K)+xg1(48K)+h2b

  const int tid  = threadIdx.x;
  const int wave = tid >> 6;
  const int lane = tid & 63;
  const int q    = lane >> 4;
  const int c16  = lane & 15;
  const int bid  = blockIdx.x;
  const uint32_t lane16 = (uint32_t)(lane << 4);
  int dead = 0;

#define BARRIER() asm volatile("s_waitcnt lgkmcnt(0)\n\ts_barrier" ::: "memory")
#define ISSUE3(sl, oR, oZ, oN)                                              \
  asm volatile("global_load_dwordx4 %0, %3, %6\n\t"                         \
               "global_load_dwordx4 %1, %4, %6\n\t"                         \
               "global_load_dwordx4 %2, %5, %6"                             \
               : "=&v"(rr_[sl]), "=&v"(rz_[sl]), "=&v"(rn_[sl])             \
               : "v"((uint32_t)(oR)), "v"((uint32_t)(oZ)),                  \
                 "v"((uint32_t)(oN)), "s"(ws)                               \
               : "memory")
#define WAIT3(sl, NSTR)                                                     \
  asm volatile("s_waitcnt vmcnt(" NSTR ")"                                  \
               : "+v"(rr_[sl]), "+v"(rz_[sl]), "+v"(rn_[sl]) :: "memory")
#define SCLOAD4(dst, off)                                                   \
  asm volatile("global_load_dwordx4 %0, %1, %2 sc0 sc1"                     \
               : "=&v"(dst) : "v"((uint32_t)(off)), "s"(ws) : "memory")
#define SCSTORE4(off, val)                                                  \
  asm volatile("global_store_dwordx4 %0, %1, %2 sc0 sc1"                    \
               :: "v"((uint32_t)(off)), "v"(val), "s"(ws) : "memory")
#define SCSTORE2(off, val)                                                  \
  asm volatile("global_store_dwordx2 %0, %1, %2 sc0 sc1"                    \
               :: "v"((uint32_t)(off)), "v"(val), "s"(ws) : "memory")
#define PUBLISH(off, val)                                                   \
  asm volatile("global_store_dword %0, %1, %2 sc0 sc1"                      \
               :: "v"((uint32_t)(off)), "v"((uint32_t)(val)), "s"(ws)       \
               : "memory")
#define POLL(off, target)                                                   \
  do {                                                                      \
    int tgt = (target);                                                     \
    if (tgt > 0) {                                                          \
      int it = 0, bound = dead ? 64 : (1 << 17);                            \
      for (;;) {                                                            \
        uint32_t v_;                                                        \
        asm volatile("global_load_dword %0, %1, %2 sc0 sc1\n\t"             \
                     "s_waitcnt vmcnt(0)"                                   \
                     : "=&v"(v_) : "v"((uint32_t)(off)), "s"(ws)            \
                     : "memory");                                           \
        if ((int)v_ >= tgt) break;                                          \
        if (++it >= bound) { dead = 1; break; }                             \
        __builtin_amdgcn_s_sleep(2);                                        \
      }                                                                     \
    }                                                                       \
  } while (0)

  // =========================================================================
  if (bid < 64) {
    // ----------------------------- Stage A: layer 0 -----------------------
    const int g = bid, row0 = g * 32;
    unsigned short (*h1b)[264] = (unsigned short (*)[264])smem;       // [2*32][264]
    unsigned short (*xs)[32]   = (unsigned short (*)[32])(smem + 33792); // [2*32][32]
    for (int i = tid; i < 2 * 32 * 264; i += 1024) ((unsigned short*)smem)[i] = 0;
    for (int i = tid; i < 2 * 32 * 32; i += 1024) ((unsigned short*)(smem + 33792))[i] = 0;
    const int c = wave * 16 + c16;
    const float brc = bih0[c] + bhh0[c];
    const float bzc = bih0[HID + c] + bhh0[HID + c];
    const float bni = bih0[2 * HID + c];
    const float bnh = bhh0[2 * HID + c];
    {  // x(0)
      int r = tid & 31, cc = tid >> 5;
      float xv = x[(size_t)(row0 + r) * IN_DIM + (cc < 18 ? cc : 17)];
      if (cc < 18) xs[r][cc] = f2bf(xv);
    }
    __syncthreads();

    const uint32_t b0r = (uint32_t)((wave * KT0) << 10);
    const uint32_t b0z = (uint32_t)(((16 + wave) * KT0) << 10);
    const uint32_t b0n = (uint32_t)(((32 + wave) * KT0) << 10);
    frag_ab rr_[3], rz_[3], rn_[3];
    float h1m[2][4] = {{0, 0, 0, 0}, {0, 0, 0, 0}};
    uint32_t xvu = 0;
    #pragma unroll
    for (int i = 0; i < 3; ++i)
      ISSUE3(i, b0r + i * 1024 + lane16, b0z + i * 1024 + lane16,
                b0n + i * 1024 + lane16);

    for (int tp = 0; tp < 64; ++tp) {
      const int t0 = tp * 2;
      #pragma unroll
      for (int hf = 0; hf < 2; ++hf) {
        const int p = hf, pn = hf ^ 1;
        {  // x(t0+hf+1) prefetch (plain cached load)
          int t1c = t0 + hf + 1; if (t1c > T_STEPS - 1) t1c = T_STEPS - 1;
          int r = tid & 31, cc = tid >> 5;
          uint32_t xo = (uint32_t)((((t1c * BATCH) + row0 + r) * IN_DIM +
                                    (cc < 18 ? cc : 17)) * 4);
          asm volatile("global_load_dword %0, %1, %2"
                       : "=&v"(xvu) : "v"(xo), "s"(x) : "memory");
        }
        f32x4 a_r[2] = {{0,0,0,0},{0,0,0,0}}, a_z[2] = {{0,0,0,0},{0,0,0,0}};
        f32x4 a_nx[2] = {{0,0,0,0},{0,0,0,0}}, a_nh[2] = {{0,0,0,0},{0,0,0,0}};
        #pragma unroll
        for (int i = 0; i < KT0; ++i) {
          const int sl = i % 3;
          WAIT3(sl, "6");
          frag_ab A0, A1v;
          if (i == 0) {
            A0  = *(const frag_ab*)&xs[p * 32 + c16][q * 8];
            A1v = *(const frag_ab*)&xs[p * 32 + 16 + c16][q * 8];
          } else {
            A0  = *(const frag_ab*)&h1b[p * 32 + c16][(i - 1) * 32 + q * 8];
            A1v = *(const frag_ab*)&h1b[p * 32 + 16 + c16][(i - 1) * 32 + q * 8];
          }
          a_r[0] = mfma16(A0, rr_[sl], a_r[0]);  a_r[1] = mfma16(A1v, rr_[sl], a_r[1]);
          a_z[0] = mfma16(A0, rz_[sl], a_z[0]);  a_z[1] = mfma16(A1v, rz_[sl], a_z[1]);
          if (i == 0) { a_nx[0] = mfma16(A0, rn_[sl], a_nx[0]);
                        a_nx[1] = mfma16(A1v, rn_[sl], a_nx[1]); }
          else        { a_nh[0] = mfma16(A0, rn_[sl], a_nh[0]);
                        a_nh[1] = mfma16(A1v, rn_[sl], a_nh[1]); }
          const int nk = (i + 3) % KT0;
          ISSUE3(sl, b0r + nk * 1024 + lane16, b0z + nk * 1024 + lane16,
                     b0n + nk * 1024 + lane16);
        }
        // epilogue: x stage + h1 update
        { int r = tid & 31, cc = tid >> 5;
          if (cc < 18) xs[pn * 32 + r][cc] = f2bf(__uint_as_float(xvu)); }
        #pragma unroll
        for (int mt = 0; mt < 2; ++mt)
          #pragma unroll
          for (int rrI = 0; rrI < 4; ++rrI) {
            const int row = mt * 16 + q * 4 + rrI;
            float rg = sigmoidf_(a_r[mt][rrI] + brc);
            float zg = sigmoidf_(a_z[mt][rrI] + bzc);
            float ng = tanhf_(a_nx[mt][rrI] + bni + rg * (a_nh[mt][rrI] + bnh));
            float hn = (1.f - zg) * ng + zg * h1m[mt][rrI];
            h1m[mt][rrI] = hn;
            h1b[pn * 32 + row][c] = f2bf(hn);
          }
        BARRIER();
      }
      // export BOTH halves: h1(t0) in h1b[1] (pn of hf=0), h1(t0+1) in h1b[0]
      { const int mt = wave >> 3, kt = wave & 7;
        frag_ab fa0 = *(const frag_ab*)&h1b[32 + mt * 16 + c16][kt * 32 + q * 8];
        SCSTORE4(H1SLOT(t0, g) + (uint32_t)(wave * 1024 + lane * 16), fa0);
        frag_ab fa1 = *(const frag_ab*)&h1b[mt * 16 + c16][kt * 32 + q * 8];
        SCSTORE4(H1SLOT(t0 + 1, g) + (uint32_t)(wave * 1024 + lane * 16), fa1); }
      asm volatile("s_waitcnt vmcnt(0)" ::: "memory");
      BARRIER();
      if (tid == 0) { PUBLISH(CNTA(g), tp + 1); POLL(CNTB(g), tp - 1); }
      BARRIER();
    }

  } else if (bid < 128) {
    // ------------------------ Stage B: xg1 = h1 @ W_ih1^T -----------------
    const int g = bid - 64;
    unsigned short* slab = (unsigned short*)smem;   // [2][16384 B] frag slabs
    const int c = wave * 16 + c16;
    const float bri = bih1[c], bzi = bih1[HID + c], bni = bih1[2 * HID + c];

    const uint32_t b1r = (uint32_t)((L0_FRAGS + wave * KT1) << 10);
    const uint32_t b1z = (uint32_t)((L0_FRAGS + (16 + wave) * KT1) << 10);
    const uint32_t b1n = (uint32_t)((L0_FRAGS + (32 + wave) * KT1) << 10);
    frag_ab rr_[4], rz_[4], rn_[4];
    #pragma unroll
    for (int i = 0; i < 4; ++i)
      ISSUE3(i, b1r + i * 1024 + lane16, b1z + i * 1024 + lane16,
                b1n + i * 1024 + lane16);

    if (tid == 0) POLL(CNTA(g), 1);
    BARRIER();
    { uint4v u; SCLOAD4(u, H1SLOT(0, g) + tid * 16);
      asm volatile("s_waitcnt vmcnt(0)" : "+v"(u) :: "memory");
      *(uint4v*)((char*)slab + tid * 16) = u; }
    { uint4v u; SCLOAD4(u, H1SLOT(1, g) + tid * 16);
      asm volatile("s_waitcnt vmcnt(0)" : "+v"(u) :: "memory");
      *(uint4v*)((char*)slab + 16384 + tid * 16) = u; }
    if (tid == 0) POLL(CNTA(g), 2);
    __syncthreads();
    __builtin_amdgcn_sched_barrier(0);

    for (int u = 0; u < 64; ++u) {
      const int t0 = u * 2;
      #pragma unroll
      for (int hf = 0; hf < 2; ++hf) {
        uint4v stg = {0, 0, 0, 0};
        // pair u+1, half hf (u=63: stale ring slot, stored but never read)
        SCLOAD4(stg, H1SLOT(t0 + 2 + hf, g) + tid * 16);
        f32x4 acc[3][2];
        #pragma unroll
        for (int ga = 0; ga < 3; ++ga) { acc[ga][0] = (f32x4){0,0,0,0};
                                         acc[ga][1] = (f32x4){0,0,0,0}; }
        // R0's 8-tile K-loop, wait "9" at js>=3 (queue: [stg]+3 groups = 10)
        #pragma unroll
        for (int js = 0; js < 8; ++js) {
          const int sl = js & 3;
          if (js >= 3) WAIT3(sl, "9");
          frag_ab A0  = *(const frag_ab*)((char*)slab + hf * 16384 + (js * 64 + lane) * 16);
          frag_ab A1v = *(const frag_ab*)((char*)slab + hf * 16384 + ((8 + js) * 64 + lane) * 16);
          acc[0][0] = mfma16(A0, rr_[sl], acc[0][0]); acc[0][1] = mfma16(A1v, rr_[sl], acc[0][1]);
          acc[1][0] = mfma16(A0, rz_[sl], acc[1][0]); acc[1][1] = mfma16(A1v, rz_[sl], acc[1][1]);
          acc[2][0] = mfma16(A0, rn_[sl], acc[2][0]); acc[2][1] = mfma16(A1v, rn_[sl], acc[2][1]);
          const int nk = (js + 4) & 7;
          ISSUE3(sl, b1r + nk * 1024 + lane16, b1z + nk * 1024 + lane16,
                     b1n + nk * 1024 + lane16);
        }
        // export xg(t0+hf) (swizzled)
        #pragma unroll
        for (int ga = 0; ga < 3; ++ga) {
          const float bb = (ga == 0) ? bri : (ga == 1) ? bzi : bni;
          const int col = ga * 256 + c;
          #pragma unroll
          for (int mt = 0; mt < 2; ++mt) {
            uint2v uu;
            uu[0] = (uint32_t)f2bf(acc[ga][mt][0] + bb) |
                    ((uint32_t)f2bf(acc[ga][mt][1] + bb) << 16);
            uu[1] = (uint32_t)f2bf(acc[ga][mt][2] + bb) |
                    ((uint32_t)f2bf(acc[ga][mt][3] + bb) << 16);
            SCSTORE2(XGSLOT(t0 + hf, g) + XGOFFS(col, (mt * 16 + q * 4) * 2), uu);
          }
        }
        // drain (stg + exports + weight prefetches) BEFORE barrier -> the
        // pair-end publish is ordered after every wave's global reads.
        asm volatile("s_waitcnt vmcnt(0)" : "+v"(stg) :: "memory");
        BARRIER();
        *(uint4v*)((char*)slab + hf * 16384 + tid * 16) = stg;
      }
      if (tid == 0) {
        PUBLISH(CNTB(g), u + 1);
        if (u <= 61) POLL(CNTA(g), u + 3);
        POLL(CNTC(g), u - 1);
      }
      BARRIER();
    }

  } else {
    // ---------------- Stage C: h2 recurrence (W_hh1) + gates + FC ---------
    const int g = bid - 128, row0 = g * 32;
    unsigned short* xg0 = (unsigned short*)smem;                      // 48 KB
    unsigned short* xg1 = (unsigned short*)(smem + 49152);            // 48 KB
    unsigned short (*h2b)[264] = (unsigned short (*)[264])(smem + 98304);
    for (int i = tid; i < 2 * 32 * 264; i += 1024)
      ((unsigned short*)(smem + 98304))[i] = 0;
    const int c = wave * 16 + c16;
    const float brh = bhh1[c], bzh = bhh1[HID + c], bnh = bhh1[2 * HID + c];

    const uint32_t bCr = (uint32_t)((L0_FRAGS + wave * KT1 + 8) << 10);
    const uint32_t bCz = (uint32_t)((L0_FRAGS + (16 + wave) * KT1 + 8) << 10);
    const uint32_t bCn = (uint32_t)((L0_FRAGS + (32 + wave) * KT1 + 8) << 10);
    frag_ab rr_[4], rz_[4], rn_[4];
    #pragma unroll
    for (int i = 0; i < 4; ++i)
      ISSUE3(i, bCr + i * 1024 + lane16, bCz + i * 1024 + lane16,
                bCn + i * 1024 + lane16);

    if (tid == 0) POLL(CNTB(g), 1);
    BARRIER();
    { uint4v u0, u1, u2;
      SCLOAD4(u0, XGSLOT(0, g) + tid * 16);
      SCLOAD4(u1, XGSLOT(0, g) + 16384 + tid * 16);
      SCLOAD4(u2, XGSLOT(0, g) + 32768 + tid * 16);
      asm volatile("s_waitcnt vmcnt(0)" : "+v"(u0), "+v"(u1), "+v"(u2) :: "memory");
      *(uint4v*)((char*)xg0 + tid * 16) = u0;
      *(uint4v*)((char*)xg0 + 16384 + tid * 16) = u1;
      *(uint4v*)((char*)xg0 + 32768 + tid * 16) = u2; }
    { uint4v u0, u1, u2;
      SCLOAD4(u0, XGSLOT(1, g) + tid * 16);
      SCLOAD4(u1, XGSLOT(1, g) + 16384 + tid * 16);
      SCLOAD4(u2, XGSLOT(1, g) + 32768 + tid * 16);
      asm volatile("s_waitcnt vmcnt(0)" : "+v"(u0), "+v"(u1), "+v"(u2) :: "memory");
      *(uint4v*)((char*)xg1 + tid * 16) = u0;
      *(uint4v*)((char*)xg1 + 16384 + tid * 16) = u1;
      *(uint4v*)((char*)xg1 + 32768 + tid * 16) = u2; }
    if (tid == 0) POLL(CNTB(g), 2);
    __syncthreads();
    __builtin_amdgcn_sched_barrier(0);

    float h2m[2][4] = {{0, 0, 0, 0}, {0, 0, 0, 0}};

    for (int v = 0; v < 64; ++v) {
      const int t0 = v * 2;
      #pragma unroll
      for (int hf = 0; hf < 2; ++hf) {
        uint4v s0 = {0,0,0,0}, s1 = {0,0,0,0}, s2 = {0,0,0,0};
        // pair v+1, half hf (v=63: stale ring slot, stored but never read)
        SCLOAD4(s0, XGSLOT(t0 + 2 + hf, g) + tid * 16);
        SCLOAD4(s1, XGSLOT(t0 + 2 + hf, g) + 16384 + tid * 16);
        SCLOAD4(s2, XGSLOT(t0 + 2 + hf, g) + 32768 + tid * 16);
        f32x4 acc[3][2];
        #pragma unroll
        for (int ga = 0; ga < 3; ++ga) { acc[ga][0] = (f32x4){0,0,0,0};
                                         acc[ga][1] = (f32x4){0,0,0,0}; }
        // R0's 8-tile K-loop, wait "9" at js>=3 (queue: [s0-2]+3 groups = 12)
        #pragma unroll
        for (int js = 0; js < 8; ++js) {
          const int sl = js & 3;
          if (js >= 3) WAIT3(sl, "9");
          frag_ab A0  = *(const frag_ab*)&h2b[hf * 32 + c16][js * 32 + q * 8];
          frag_ab A1v = *(const frag_ab*)&h2b[hf * 32 + 16 + c16][js * 32 + q * 8];
          acc[0][0] = mfma16(A0, rr_[sl], acc[0][0]); acc[0][1] = mfma16(A1v, rr_[sl], acc[0][1]);
          acc[1][0] = mfma16(A0, rz_[sl], acc[1][0]); acc[1][1] = mfma16(A1v, rz_[sl], acc[1][1]);
          acc[2][0] = mfma16(A0, rn_[sl], acc[2][0]); acc[2][1] = mfma16(A1v, rn_[sl], acc[2][1]);
          const int nk = (js + 4) & 7;
          ISSUE3(sl, bCr + nk * 1024 + lane16, bCz + nk * 1024 + lane16,
                     bCn + nk * 1024 + lane16);
        }
        // epilogue: read xg(t0+hf) (swizzled), gates, h2 update
        const unsigned short* xgb = hf ? xg1 : xg0;
        #pragma unroll
        for (int mt = 0; mt < 2; ++mt) {
          uint2v ur = *(const uint2v*)((const char*)xgb + XGOFFS(0 * 256 + c, (mt * 16 + q * 4) * 2));
          uint2v uz = *(const uint2v*)((const char*)xgb + XGOFFS(1 * 256 + c, (mt * 16 + q * 4) * 2));
          uint2v un = *(const uint2v*)((const char*)xgb + XGOFFS(2 * 256 + c, (mt * 16 + q * 4) * 2));
          #pragma unroll
          for (int rrI = 0; rrI < 4; ++rrI) {
            const int row = mt * 16 + q * 4 + rrI;
            const uint32_t wr = (rrI < 2) ? ur[0] : ur[1];
            const uint32_t wz = (rrI < 2) ? uz[0] : uz[1];
            const uint32_t wn = (rrI < 2) ? un[0] : un[1];
            const int sh = (rrI & 1) * 16;
            float xr = bf2f((unsigned short)(wr >> sh));
            float xz = bf2f((unsigned short)(wz >> sh));
            float xn = bf2f((unsigned short)(wn >> sh));
            float rg = sigmoidf_(xr + acc[0][mt][rrI] + brh);
            float zg = sigmoidf_(xz + acc[1][mt][rrI] + bzh);
            float ng = tanhf_(xn + rg * (acc[2][mt][rrI] + bnh));
            float hn = (1.f - zg) * ng + zg * h2m[mt][rrI];
            h2m[mt][rrI] = hn;
            h2b[(hf ^ 1) * 32 + row][c] = f2bf(hn);
          }
        }
        // drain BEFORE barrier (publish ordering), then overwrite xg(hf)
        asm volatile("s_waitcnt vmcnt(0)" : "+v"(s0), "+v"(s1), "+v"(s2) :: "memory");
        BARRIER();
        { unsigned short* xgw = hf ? xg1 : xg0;
          *(uint4v*)((char*)xgw + tid * 16) = s0;
          *(uint4v*)((char*)xgw + 16384 + tid * 16) = s1;
          *(uint4v*)((char*)xgw + 32768 + tid * 16) = s2; }
      }
      if (tid == 0) {
        PUBLISH(CNTC(g), v + 1);
        if (v <= 61) POLL(CNTB(g), v + 3);
      }
      BARRIER();
    }

    // FC head: h2(127) = pair 63 half 1 -> h2b parity 0
    if (tid < 128) {
      const int row = tid >> 2, o = tid & 3;
      float acc2 = fcb[o];
      #pragma unroll 8
      for (int k = 0; k < HID; ++k)
        acc2 += bf2f(h2b[row][k]) * fcw[o * HID + k];
      float sg = 1.f / (1.f + __expf(-acc2));
      out[(size_t)(row0 + row) * 4 + o] = sg * 2.f - 1.f;
    }
  }
#undef BARRIER
#undef ISSUE3
#undef WAIT3
#undef SCLOAD4
#undef SCSTORE4
#undef SCSTORE2
#undef PUBLISH
#undef POLL
}

extern "C" void kernel_launch(void* const* d_in, const int* in_sizes, int n_in,
                              void* d_out, int out_size, void* d_ws, size_t ws_size,
                              hipStream_t stream) {
  const float* x    = (const float*)d_in[0];
  const float* Wih0 = (const float*)d_in[1];
  const float* Whh0 = (const float*)d_in[2];
  const float* bih0 = (const float*)d_in[3];
  const float* bhh0 = (const float*)d_in[4];
  const float* Wih1 = (const float*)d_in[5];
  const float* Whh1 = (const float*)d_in[6];
  const float* bih1 = (const float*)d_in[7];
  const float* bhh1 = (const float*)d_in[8];
  const float* fcw  = (const float*)d_in[9];
  const float* fcb  = (const float*)d_in[10];

  unsigned short* wq = (unsigned short*)d_ws;
  uint32_t* cnt = (uint32_t*)((char*)d_ws + CNT_OFF);

  repack_w<<<(TOT_FRAGS * 64 + 255) / 256, 256, 0, stream>>>(Wih0, Whh0, Wih1, Whh1, wq);
  clear_cnt<<<12, 256, 0, stream>>>(cnt);
  gru_pipe<<<192, 1024, 0, stream>>>(x, bih0, bhh0, bih1, bhh1, fcw, fcb,
                                     (char*)d_ws, (float*)d_out);
}

// Round 9
// 929.947 us; speedup vs baseline: 1.3395x; 1.3395x over previous
//
#include <hip/hip_runtime.h>
#include <hip/hip_bf16.h>
#include <stdint.h>

// Problem constants
#define T_STEPS 128
#define BATCH   2048
#define IN_DIM  18
#define HID     256

// Fragment repack (same layout as R3)
#define NT   48
#define KT0  9
#define KT1  16
#define L0_FRAGS 432
#define L1_FRAGS 768
#define TOT_FRAGS 1200

// d_ws layout (total need ~17.7 MB)
#define CNT_OFF  1310720u
#define CNTA(g)  (CNT_OFF + (uint32_t)(g) * 64u)
#define CNTB(g)  (CNT_OFF + 4096u + (uint32_t)(g) * 64u)
#define CNTC(g)  (CNT_OFF + 8192u + (uint32_t)(g) * 64u)
#define H1_OFF   1441792u
#define H1SLOT(t, g) (H1_OFF + (uint32_t)(((((t) & 3) * 64) + (g)) * 16384))
#define XG_OFF   5898240u
#define XGSLOT(t, g) (XG_OFF + (uint32_t)(((((t) & 3) * 64) + (g)) * 49152))

// xg layout inside a slot: col-major 64B rows, XOR-swizzled to break the
// 8-way LDS bank conflict on C's gate reads (R2 delta; passed 3x, numerics
// identical). Writer (B's global stores) and reader (C's LDS reads) apply
// the same mapping; C's staging copies slot bytes linearly.
#define XGOFFS(col, inner) ((uint32_t)((col) * 64 + ((inner) ^ (((col) & 7) << 3))))

using frag_ab = __attribute__((ext_vector_type(8))) short;
using f32x4   = __attribute__((ext_vector_type(4))) float;
using uint4v  = __attribute__((ext_vector_type(4))) unsigned int;
using uint2v  = __attribute__((ext_vector_type(2))) unsigned int;

__device__ __forceinline__ unsigned short f2bf(float f) {
  unsigned int u = __float_as_uint(f);
  u = (u + 0x7fffu + ((u >> 16) & 1u)) >> 16;  // RNE
  return (unsigned short)u;
}
__device__ __forceinline__ float bf2f(unsigned short v) {
  return __uint_as_float((uint32_t)v << 16);
}
__device__ __forceinline__ float sigmoidf_(float v) {
  return 1.f / (1.f + __expf(-v));
}
__device__ __forceinline__ float tanhf_(float v) {
  float a = fabsf(v);
  float e = __expf(-2.f * a);
  float r = (1.f - e) / (1.f + e);
  return v < 0.f ? -r : r;
}
__device__ __forceinline__ f32x4 mfma16(frag_ab a, frag_ab b, f32x4 c) {
  return __builtin_amdgcn_mfma_f32_16x16x32_bf16(a, b, c, 0, 0, 0);
}

// ---------------------------------------------------------------------------
// Prologue 1: fp32 weights -> bf16 MFMA B-fragments (layout as R3).
// ---------------------------------------------------------------------------
__global__ __launch_bounds__(256) void repack_w(
    const float* __restrict__ Wih0, const float* __restrict__ Whh0,
    const float* __restrict__ Wih1, const float* __restrict__ Whh1,
    unsigned short* __restrict__ wq)
{
  int g = blockIdx.x * 256 + threadIdx.x;
  if (g >= TOT_FRAGS * 64) return;
  int f = g >> 6;
  int L = g & 63;
  int q = L >> 4, c16 = L & 15;
  unsigned short v[8];
  if (f < L0_FRAGS) {
    int n = f / KT0, kt = f - n * KT0;
    int col = n * 16 + c16;
    if (kt == 0) {
      #pragma unroll
      for (int j = 0; j < 8; ++j) {
        int k = q * 8 + j;
        v[j] = (k < IN_DIM) ? f2bf(Wih0[col * IN_DIM + k]) : (unsigned short)0;
      }
    } else {
      int kb = (kt - 1) * 32 + q * 8;
      #pragma unroll
      for (int j = 0; j < 8; ++j) v[j] = f2bf(Whh0[col * HID + kb + j]);
    }
  } else {
    int f1 = f - L0_FRAGS;
    int n = f1 / KT1, kt = f1 - n * KT1;
    int col = n * 16 + c16;
    const float* __restrict__ W = (kt < 8) ? Wih1 : Whh1;
    int kb = (kt & 7) * 32 + q * 8;
    #pragma unroll
    for (int j = 0; j < 8; ++j) v[j] = f2bf(W[col * HID + kb + j]);
  }
  frag_ab pv;
  #pragma unroll
  for (int j = 0; j < 8; ++j) pv[j] = (short)v[j];
  *(frag_ab*)((char*)wq + ((size_t)f << 10) + (size_t)(L << 4)) = pv;
}

// ---------------------------------------------------------------------------
// Prologue 2: zero the counters (d_ws poisoned each launch).
// ---------------------------------------------------------------------------
__global__ __launch_bounds__(256) void clear_cnt(uint32_t* __restrict__ c) {
  int i = blockIdx.x * 256 + threadIdx.x;
  if (i < 3072) c[i] = 0;
}

// ---------------------------------------------------------------------------
// 3-stage pipeline: A (layer0) -> B (h1 @ W_ih1^T) -> C (h2 recurrence + FC).
// EXACT R0 schedule (1026us verified) with two strictly-local deltas:
//  1. poll-overlap: tid0 issues its consumer POLL BEFORE the end-of-step
//     vmcnt(0) drain, so the poll's L3 RTT overlaps all waves' export
//     drains instead of following them serially. PUBLISH stays after the
//     post-drain barrier (correctness identical: the poll result is only
//     consumed at the NEXT step's export, enforced by the trailing barrier;
//     the poll->publish dependency chain is acyclic across stages).
//  2. xg XOR-swizzle (XGOFFS) on B's exports + C's gate reads (from R2;
//     bank conflicts 3.1e7 -> 2.2e7, numerics unchanged).
// ---------------------------------------------------------------------------
__global__ __launch_bounds__(1024) void gru_pipe(
    const float* __restrict__ x,
    const float* __restrict__ bih0, const float* __restrict__ bhh0,
    const float* __restrict__ bih1, const float* __restrict__ bhh1,
    const float* __restrict__ fcw,  const float* __restrict__ fcb,
    char* __restrict__ ws,
    float* __restrict__ out)
{
  __shared__ __align__(16) char smem[82944];   // 81 KB -> 1 block/CU

  const int tid  = threadIdx.x;
  const int wave = tid >> 6;
  const int lane = tid & 63;
  const int q    = lane >> 4;
  const int c16  = lane & 15;
  const int bid  = blockIdx.x;
  const uint32_t lane16 = (uint32_t)(lane << 4);
  int dead = 0;

#define BARRIER() asm volatile("s_waitcnt lgkmcnt(0)\n\ts_barrier" ::: "memory")
#define ISSUE3(sl, oR, oZ, oN)                                              \
  asm volatile("global_load_dwordx4 %0, %3, %6\n\t"                         \
               "global_load_dwordx4 %1, %4, %6\n\t"                         \
               "global_load_dwordx4 %2, %5, %6"                             \
               : "=&v"(rr_[sl]), "=&v"(rz_[sl]), "=&v"(rn_[sl])             \
               : "v"((uint32_t)(oR)), "v"((uint32_t)(oZ)),                  \
                 "v"((uint32_t)(oN)), "s"(ws)                               \
               : "memory")
#define WAIT3(sl, NSTR)                                                     \
  asm volatile("s_waitcnt vmcnt(" NSTR ")"                                  \
               : "+v"(rr_[sl]), "+v"(rz_[sl]), "+v"(rn_[sl]) :: "memory")
#define SCLOAD4(dst, off)                                                   \
  asm volatile("global_load_dwordx4 %0, %1, %2 sc0 sc1"                     \
               : "=&v"(dst) : "v"((uint32_t)(off)), "s"(ws) : "memory")
#define SCSTORE4(off, val)                                                  \
  asm volatile("global_store_dwordx4 %0, %1, %2 sc0 sc1"                    \
               :: "v"((uint32_t)(off)), "v"(val), "s"(ws) : "memory")
#define SCSTORE2(off, val)                                                  \
  asm volatile("global_store_dwordx2 %0, %1, %2 sc0 sc1"                    \
               :: "v"((uint32_t)(off)), "v"(val), "s"(ws) : "memory")
#define PUBLISH(off, val)                                                   \
  asm volatile("global_store_dword %0, %1, %2 sc0 sc1"                      \
               :: "v"((uint32_t)(off)), "v"((uint32_t)(val)), "s"(ws)       \
               : "memory")
#define POLL(off, target)                                                   \
  do {                                                                      \
    int tgt = (target);                                                     \
    if (tgt > 0) {                                                          \
      int it = 0, bound = dead ? 64 : (1 << 17);                            \
      for (;;) {                                                            \
        uint32_t v_;                                                        \
        asm volatile("global_load_dword %0, %1, %2 sc0 sc1\n\t"             \
                     "s_waitcnt vmcnt(0)"                                   \
                     : "=&v"(v_) : "v"((uint32_t)(off)), "s"(ws)            \
                     : "memory");                                           \
        if ((int)v_ >= tgt) break;                                          \
        if (++it >= bound) { dead = 1; break; }                             \
        __builtin_amdgcn_s_sleep(2);                                        \
      }                                                                     \
    }                                                                       \
  } while (0)

  // =========================================================================
  if (bid < 64) {
    // ----------------------------- Stage A: layer 0 -----------------------
    const int g = bid, row0 = g * 32;
    unsigned short (*h1b)[264] = (unsigned short (*)[264])smem;       // [2*32][264]
    unsigned short (*xs)[32]   = (unsigned short (*)[32])(smem + 33792); // [2*32][32]
    for (int i = tid; i < 2 * 32 * 264; i += 1024) ((unsigned short*)smem)[i] = 0;
    for (int i = tid; i < 2 * 32 * 32; i += 1024) ((unsigned short*)(smem + 33792))[i] = 0;
    const int c = wave * 16 + c16;
    const float brc = bih0[c] + bhh0[c];
    const float bzc = bih0[HID + c] + bhh0[HID + c];
    const float bni = bih0[2 * HID + c];
    const float bnh = bhh0[2 * HID + c];
    {  // x(0)
      int r = tid & 31, cc = tid >> 5;
      float xv = x[(size_t)(row0 + r) * IN_DIM + (cc < 18 ? cc : 17)];
      if (cc < 18) xs[r][cc] = f2bf(xv);
    }
    __syncthreads();

    const uint32_t b0r = (uint32_t)((wave * KT0) << 10);
    const uint32_t b0z = (uint32_t)(((16 + wave) * KT0) << 10);
    const uint32_t b0n = (uint32_t)(((32 + wave) * KT0) << 10);
    frag_ab rr_[3], rz_[3], rn_[3];
    float h1m[2][4] = {{0, 0, 0, 0}, {0, 0, 0, 0}};
    uint32_t xvu = 0;
    #pragma unroll
    for (int i = 0; i < 3; ++i)
      ISSUE3(i, b0r + i * 1024 + lane16, b0z + i * 1024 + lane16,
                b0n + i * 1024 + lane16);

    for (int t = 0; t < T_STEPS; ++t) {
      const int p = t & 1, pn = p ^ 1;
      {  // x(t+1) prefetch (plain cached load)
        int t1 = (t + 1 < T_STEPS) ? t + 1 : T_STEPS - 1;
        int r = tid & 31, cc = tid >> 5;
        uint32_t xo = (uint32_t)((((t1 * BATCH) + row0 + r) * IN_DIM +
                                  (cc < 18 ? cc : 17)) * 4);
        asm volatile("global_load_dword %0, %1, %2"
                     : "=&v"(xvu) : "v"(xo), "s"(x) : "memory");
      }
      f32x4 a_r[2] = {{0,0,0,0},{0,0,0,0}}, a_z[2] = {{0,0,0,0},{0,0,0,0}};
      f32x4 a_nx[2] = {{0,0,0,0},{0,0,0,0}}, a_nh[2] = {{0,0,0,0},{0,0,0,0}};
      #pragma unroll
      for (int i = 0; i < KT0; ++i) {
        const int sl = i % 3;
        WAIT3(sl, "6");
        frag_ab A0, A1v;
        if (i == 0) {
          A0  = *(const frag_ab*)&xs[p * 32 + c16][q * 8];
          A1v = *(const frag_ab*)&xs[p * 32 + 16 + c16][q * 8];
        } else {
          A0  = *(const frag_ab*)&h1b[p * 32 + c16][(i - 1) * 32 + q * 8];
          A1v = *(const frag_ab*)&h1b[p * 32 + 16 + c16][(i - 1) * 32 + q * 8];
        }
        a_r[0] = mfma16(A0, rr_[sl], a_r[0]);  a_r[1] = mfma16(A1v, rr_[sl], a_r[1]);
        a_z[0] = mfma16(A0, rz_[sl], a_z[0]);  a_z[1] = mfma16(A1v, rz_[sl], a_z[1]);
        if (i == 0) { a_nx[0] = mfma16(A0, rn_[sl], a_nx[0]);
                      a_nx[1] = mfma16(A1v, rn_[sl], a_nx[1]); }
        else        { a_nh[0] = mfma16(A0, rn_[sl], a_nh[0]);
                      a_nh[1] = mfma16(A1v, rn_[sl], a_nh[1]); }
        const int nk = (i + 3) % KT0;
        ISSUE3(sl, b0r + nk * 1024 + lane16, b0z + nk * 1024 + lane16,
                   b0n + nk * 1024 + lane16);
      }
      // epilogue: x(t+1) stage + h1 update
      { int r = tid & 31, cc = tid >> 5;
        if (cc < 18) xs[pn * 32 + r][cc] = f2bf(__uint_as_float(xvu)); }
      #pragma unroll
      for (int mt = 0; mt < 2; ++mt)
        #pragma unroll
        for (int rrI = 0; rrI < 4; ++rrI) {
          const int row = mt * 16 + q * 4 + rrI;
          float rg = sigmoidf_(a_r[mt][rrI] + brc);
          float zg = sigmoidf_(a_z[mt][rrI] + bzc);
          float ng = tanhf_(a_nx[mt][rrI] + bni + rg * (a_nh[mt][rrI] + bnh));
          float hn = (1.f - zg) * ng + zg * h1m[mt][rrI];
          h1m[mt][rrI] = hn;
          h1b[pn * 32 + row][c] = f2bf(hn);
        }
      BARRIER();
      {  // export frag j = wave (A-operand layout for B)
        const int mt = wave >> 3, kt = wave & 7;
        frag_ab fa = *(const frag_ab*)&h1b[pn * 32 + mt * 16 + c16][kt * 32 + q * 8];
        SCSTORE4(H1SLOT(t, g) + (uint32_t)(wave * 1024 + lane * 16), fa);
      }
      // poll-overlap: tid0's poll RTT rides the export drain (its own stores
      // are drained inside POLL's vmcnt(0); other waves drain concurrently).
      if (tid == 0) POLL(CNTB(g), t - 3);
      asm volatile("s_waitcnt vmcnt(0)" ::: "memory");
      BARRIER();
      if (tid == 0) PUBLISH(CNTA(g), t + 1);
      BARRIER();
    }

  } else if (bid < 128) {
    // ------------------------ Stage B: xg1 = h1 @ W_ih1^T -----------------
    const int g = bid - 64;
    unsigned short* slab = (unsigned short*)smem;   // [2][16384 B] frag slabs
    const int c = wave * 16 + c16;
    const float bri = bih1[c], bzi = bih1[HID + c], bni = bih1[2 * HID + c];
    const uint32_t b1r = (uint32_t)((L0_FRAGS + wave * KT1) << 10);
    const uint32_t b1z = (uint32_t)((L0_FRAGS + (16 + wave) * KT1) << 10);
    const uint32_t b1n = (uint32_t)((L0_FRAGS + (32 + wave) * KT1) << 10);
    frag_ab rr_[4], rz_[4], rn_[4];
    #pragma unroll
    for (int i = 0; i < 4; ++i)
      ISSUE3(i, b1r + i * 1024 + lane16, b1z + i * 1024 + lane16,
                b1n + i * 1024 + lane16);

    if (tid == 0) POLL(CNTA(g), 1);
    BARRIER();
    { uint4v u; SCLOAD4(u, H1SLOT(0, g) + tid * 16);
      asm volatile("s_waitcnt vmcnt(0)" : "+v"(u) :: "memory");
      *(uint4v*)((char*)slab + tid * 16) = u; }
    if (tid == 0) POLL(CNTA(g), 2);
    __syncthreads();

    for (int t = 0; t < T_STEPS; ++t) {
      const int p = t & 1, pn = p ^ 1;
      uint4v stg = {0, 0, 0, 0};
      const bool hasst = (t + 1 < T_STEPS);
      if (hasst) SCLOAD4(stg, H1SLOT(t + 1, g) + tid * 16);
      f32x4 acc[3][2];
      #pragma unroll
      for (int ga = 0; ga < 3; ++ga) { acc[ga][0] = (f32x4){0,0,0,0};
                                       acc[ga][1] = (f32x4){0,0,0,0}; }
      #pragma unroll
      for (int i = 0; i < 8; ++i) {
        const int sl = i & 3;
        WAIT3(sl, "9");
        frag_ab A0  = *(const frag_ab*)((char*)slab + p * 16384 + (i * 64 + lane) * 16);
        frag_ab A1v = *(const frag_ab*)((char*)slab + p * 16384 + ((8 + i) * 64 + lane) * 16);
        acc[0][0] = mfma16(A0, rr_[sl], acc[0][0]); acc[0][1] = mfma16(A1v, rr_[sl], acc[0][1]);
        acc[1][0] = mfma16(A0, rz_[sl], acc[1][0]); acc[1][1] = mfma16(A1v, rz_[sl], acc[1][1]);
        acc[2][0] = mfma16(A0, rn_[sl], acc[2][0]); acc[2][1] = mfma16(A1v, rn_[sl], acc[2][1]);
        const int nk = (i + 4) & 7;
        ISSUE3(sl, b1r + nk * 1024 + lane16, b1z + nk * 1024 + lane16,
                   b1n + nk * 1024 + lane16);
      }
      if (hasst) *(uint4v*)((char*)slab + pn * 16384 + tid * 16) = stg;
      #pragma unroll
      for (int ga = 0; ga < 3; ++ga) {
        const float bb = (ga == 0) ? bri : (ga == 1) ? bzi : bni;
        const int col = ga * 256 + c;
        #pragma unroll
        for (int mt = 0; mt < 2; ++mt) {
          uint2v u;
          u[0] = (uint32_t)f2bf(acc[ga][mt][0] + bb) |
                 ((uint32_t)f2bf(acc[ga][mt][1] + bb) << 16);
          u[1] = (uint32_t)f2bf(acc[ga][mt][2] + bb) |
                 ((uint32_t)f2bf(acc[ga][mt][3] + bb) << 16);
          SCSTORE2(XGSLOT(t, g) + XGOFFS(col, (mt * 16 + q * 4) * 2), u);
        }
      }
      // poll-overlap: polls ride the export drain.
      if (tid == 0) {
        if (t <= 125) POLL(CNTA(g), t + 3);
        POLL(CNTC(g), t - 3);
      }
      asm volatile("s_waitcnt vmcnt(0)" ::: "memory");
      BARRIER();
      if (tid == 0) PUBLISH(CNTB(g), t + 1);
      BARRIER();
    }

  } else {
    // ---------------- Stage C: h2 recurrence (W_hh1) + gates + FC ---------
    const int g = bid - 128, row0 = g * 32;
    unsigned short* xg = (unsigned short*)smem;                       // 48 KB
    unsigned short (*h2b)[264] = (unsigned short (*)[264])(smem + 49152);
    for (int i = tid; i < 2 * 32 * 264; i += 1024)
      ((unsigned short*)(smem + 49152))[i] = 0;
    const int c = wave * 16 + c16;
    const float brh = bhh1[c], bzh = bhh1[HID + c], bnh = bhh1[2 * HID + c];
    const uint32_t bCr = (uint32_t)((L0_FRAGS + wave * KT1 + 8) << 10);
    const uint32_t bCz = (uint32_t)((L0_FRAGS + (16 + wave) * KT1 + 8) << 10);
    const uint32_t bCn = (uint32_t)((L0_FRAGS + (32 + wave) * KT1 + 8) << 10);
    frag_ab rr_[4], rz_[4], rn_[4];
    float h2m[2][4] = {{0, 0, 0, 0}, {0, 0, 0, 0}};
    #pragma unroll
    for (int i = 0; i < 4; ++i)
      ISSUE3(i, bCr + i * 1024 + lane16, bCz + i * 1024 + lane16,
                bCn + i * 1024 + lane16);

    if (tid == 0) POLL(CNTB(g), 1);
    BARRIER();
    { uint4v u0, u1, u2;
      SCLOAD4(u0, XGSLOT(0, g) + tid * 16);
      SCLOAD4(u1, XGSLOT(0, g) + 16384 + tid * 16);
      SCLOAD4(u2, XGSLOT(0, g) + 32768 + tid * 16);
      asm volatile("s_waitcnt vmcnt(0)" : "+v"(u0), "+v"(u1), "+v"(u2) :: "memory");
      *(uint4v*)((char*)xg + tid * 16) = u0;
      *(uint4v*)((char*)xg + 16384 + tid * 16) = u1;
      *(uint4v*)((char*)xg + 32768 + tid * 16) = u2; }
    if (tid == 0) POLL(CNTB(g), 2);
    __syncthreads();

    for (int t = 0; t < T_STEPS; ++t) {
      const int p = t & 1, pn = p ^ 1;
      uint4v s0 = {0,0,0,0}, s1 = {0,0,0,0}, s2 = {0,0,0,0};
      const bool hasst = (t + 1 < T_STEPS);
      if (hasst) {
        SCLOAD4(s0, XGSLOT(t + 1, g) + tid * 16);
        SCLOAD4(s1, XGSLOT(t + 1, g) + 16384 + tid * 16);
        SCLOAD4(s2, XGSLOT(t + 1, g) + 32768 + tid * 16);
      }
      f32x4 acc[3][2];
      #pragma unroll
      for (int ga = 0; ga < 3; ++ga) { acc[ga][0] = (f32x4){0,0,0,0};
                                       acc[ga][1] = (f32x4){0,0,0,0}; }
      #pragma unroll
      for (int i = 0; i < 8; ++i) {
        const int sl = i & 3;
        WAIT3(sl, "9");
        frag_ab A0  = *(const frag_ab*)&h2b[p * 32 + c16][i * 32 + q * 8];
        frag_ab A1v = *(const frag_ab*)&h2b[p * 32 + 16 + c16][i * 32 + q * 8];
        acc[0][0] = mfma16(A0, rr_[sl], acc[0][0]); acc[0][1] = mfma16(A1v, rr_[sl], acc[0][1]);
        acc[1][0] = mfma16(A0, rz_[sl], acc[1][0]); acc[1][1] = mfma16(A1v, rz_[sl], acc[1][1]);
        acc[2][0] = mfma16(A0, rn_[sl], acc[2][0]); acc[2][1] = mfma16(A1v, rn_[sl], acc[2][1]);
        const int nk = (i + 4) & 7;
        ISSUE3(sl, bCr + nk * 1024 + lane16, bCz + nk * 1024 + lane16,
                   bCn + nk * 1024 + lane16);
      }
      // epilogue: read xg(t) from LDS (swizzled), gates, h2 update
      #pragma unroll
      for (int mt = 0; mt < 2; ++mt) {
        uint2v ur = *(const uint2v*)((char*)xg + XGOFFS(0 * 256 + c, (mt * 16 + q * 4) * 2));
        uint2v uz = *(const uint2v*)((char*)xg + XGOFFS(1 * 256 + c, (mt * 16 + q * 4) * 2));
        uint2v un = *(const uint2v*)((char*)xg + XGOFFS(2 * 256 + c, (mt * 16 + q * 4) * 2));
        #pragma unroll
        for (int rrI = 0; rrI < 4; ++rrI) {
          const int row = mt * 16 + q * 4 + rrI;
          const uint32_t wr = (rrI < 2) ? ur[0] : ur[1];
          const uint32_t wz = (rrI < 2) ? uz[0] : uz[1];
          const uint32_t wn = (rrI < 2) ? un[0] : un[1];
          const int sh = (rrI & 1) * 16;
          float xr = bf2f((unsigned short)(wr >> sh));
          float xz = bf2f((unsigned short)(wz >> sh));
          float xn = bf2f((unsigned short)(wn >> sh));
          float rg = sigmoidf_(xr + acc[0][mt][rrI] + brh);
          float zg = sigmoidf_(xz + acc[1][mt][rrI] + bzh);
          float ng = tanhf_(xn + rg * (acc[2][mt][rrI] + bnh));
          float hn = (1.f - zg) * ng + zg * h2m[mt][rrI];
          h2m[mt][rrI] = hn;
          h2b[pn * 32 + row][c] = f2bf(hn);
        }
      }
      BARRIER();   // all xg(t) reads done before overwrite
      // poll-overlap: tid0's poll (drains its s0-2 internally) rides the
      // other waves' staging drains + LDS stores.
      if (tid == 0 && t <= 125) POLL(CNTB(g), t + 3);
      if (hasst) {
        asm volatile("s_waitcnt vmcnt(0)" : "+v"(s0), "+v"(s1), "+v"(s2) :: "memory");
        *(uint4v*)((char*)xg + tid * 16) = s0;
        *(uint4v*)((char*)xg + 16384 + tid * 16) = s1;
        *(uint4v*)((char*)xg + 32768 + tid * 16) = s2;
      }
      BARRIER();
      if (tid == 0) PUBLISH(CNTC(g), t + 1);
      BARRIER();
    }

    // FC head from h2b parity 0 (h2(127): pn of t=127 is 0)
    if (tid < 128) {
      const int row = tid >> 2, o = tid & 3;
      float acc2 = fcb[o];
      #pragma unroll 8
      for (int k = 0; k < HID; ++k)
        acc2 += bf2f(h2b[row][k]) * fcw[o * HID + k];
      float sg = 1.f / (1.f + __expf(-acc2));
      out[(size_t)(row0 + row) * 4 + o] = sg * 2.f - 1.f;
    }
  }
#undef BARRIER
#undef ISSUE3
#undef WAIT3
#undef SCLOAD4
#undef SCSTORE4
#undef SCSTORE2
#undef PUBLISH
#undef POLL
}

extern "C" void kernel_launch(void* const* d_in, const int* in_sizes, int n_in,
                              void* d_out, int out_size, void* d_ws, size_t ws_size,
                              hipStream_t stream) {
  const float* x    = (const float*)d_in[0];
  const float* Wih0 = (const float*)d_in[1];
  const float* Whh0 = (const float*)d_in[2];
  const float* bih0 = (const float*)d_in[3];
  const float* bhh0 = (const float*)d_in[4];
  const float* Wih1 = (const float*)d_in[5];
  const float* Whh1 = (const float*)d_in[6];
  const float* bih1 = (const float*)d_in[7];
  const float* bhh1 = (const float*)d_in[8];
  const float* fcw  = (const float*)d_in[9];
  const float* fcb  = (const float*)d_in[10];

  unsigned short* wq = (unsigned short*)d_ws;
  uint32_t* cnt = (uint32_t*)((char*)d_ws + CNT_OFF);

  repack_w<<<(TOT_FRAGS * 64 + 255) / 256, 256, 0, stream>>>(Wih0, Whh0, Wih1, Whh1, wq);
  clear_cnt<<<12, 256, 0, stream>>>(cnt);
  gru_pipe<<<192, 1024, 0, stream>>>(x, bih0, bhh0, bih1, bhh1, fcw, fcb,
                                     (char*)d_ws, (float*)d_out);
}

// Round 10
// 803.573 us; speedup vs baseline: 1.5501x; 1.1573x over previous
//
#include <hip/hip_runtime.h>
#include <hip/hip_bf16.h>
#include <stdint.h>

// Problem constants
#define T_STEPS 128
#define BATCH   2048
#define IN_DIM  18
#define HID     256

// Fragment repack (same layout as R3)
#define NT   48
#define KT0  9
#define KT1  16
#define L0_FRAGS 432
#define L1_FRAGS 768
#define TOT_FRAGS 1200

// d_ws layout (total need ~17.7 MB)
#define CNT_OFF  1310720u
#define CNTA(g)  (CNT_OFF + (uint32_t)(g) * 64u)
#define CNTB(g)  (CNT_OFF + 4096u + (uint32_t)(g) * 64u)
#define CNTC(g)  (CNT_OFF + 8192u + (uint32_t)(g) * 64u)
#define H1_OFF   1441792u
#define H1SLOT(t, g) (H1_OFF + (uint32_t)(((((t) & 3) * 64) + (g)) * 16384))
#define XG_OFF   5898240u
#define XGSLOT(t, g) (XG_OFF + (uint32_t)(((((t) & 3) * 64) + (g)) * 49152))

// xg layout inside a slot: col-major 64B rows, XOR-swizzled (R9, verified).
#define XGOFFS(col, inner) ((uint32_t)((col) * 64 + ((inner) ^ (((col) & 7) << 3))))

using frag_ab = __attribute__((ext_vector_type(8))) short;
using f32x4   = __attribute__((ext_vector_type(4))) float;
using uint4v  = __attribute__((ext_vector_type(4))) unsigned int;
using uint2v  = __attribute__((ext_vector_type(2))) unsigned int;

__device__ __forceinline__ unsigned short f2bf(float f) {
  unsigned int u = __float_as_uint(f);
  u = (u + 0x7fffu + ((u >> 16) & 1u)) >> 16;  // RNE
  return (unsigned short)u;
}
__device__ __forceinline__ float bf2f(unsigned short v) {
  return __uint_as_float((uint32_t)v << 16);
}
// R10: raw v_rcp_f32 (~1 ulp) instead of IEEE div sequence (~10 VALU ops).
// absmax headroom: 5.5e-4 measured vs 2.6e-3 threshold.
__device__ __forceinline__ float sigmoidf_(float v) {
  return __builtin_amdgcn_rcpf(1.f + __expf(-v));
}
__device__ __forceinline__ float tanhf_(float v) {
  float a = fabsf(v);
  float e = __expf(-2.f * a);
  float r = (1.f - e) * __builtin_amdgcn_rcpf(1.f + e);
  return v < 0.f ? -r : r;
}
__device__ __forceinline__ f32x4 mfma16(frag_ab a, frag_ab b, f32x4 c) {
  return __builtin_amdgcn_mfma_f32_16x16x32_bf16(a, b, c, 0, 0, 0);
}

// ---------------------------------------------------------------------------
// Prologue 1: fp32 weights -> bf16 MFMA B-fragments (layout as R3).
// ---------------------------------------------------------------------------
__global__ __launch_bounds__(256) void repack_w(
    const float* __restrict__ Wih0, const float* __restrict__ Whh0,
    const float* __restrict__ Wih1, const float* __restrict__ Whh1,
    unsigned short* __restrict__ wq)
{
  int g = blockIdx.x * 256 + threadIdx.x;
  if (g >= TOT_FRAGS * 64) return;
  int f = g >> 6;
  int L = g & 63;
  int q = L >> 4, c16 = L & 15;
  unsigned short v[8];
  if (f < L0_FRAGS) {
    int n = f / KT0, kt = f - n * KT0;
    int col = n * 16 + c16;
    if (kt == 0) {
      #pragma unroll
      for (int j = 0; j < 8; ++j) {
        int k = q * 8 + j;
        v[j] = (k < IN_DIM) ? f2bf(Wih0[col * IN_DIM + k]) : (unsigned short)0;
      }
    } else {
      int kb = (kt - 1) * 32 + q * 8;
      #pragma unroll
      for (int j = 0; j < 8; ++j) v[j] = f2bf(Whh0[col * HID + kb + j]);
    }
  } else {
    int f1 = f - L0_FRAGS;
    int n = f1 / KT1, kt = f1 - n * KT1;
    int col = n * 16 + c16;
    const float* __restrict__ W = (kt < 8) ? Wih1 : Whh1;
    int kb = (kt & 7) * 32 + q * 8;
    #pragma unroll
    for (int j = 0; j < 8; ++j) v[j] = f2bf(W[col * HID + kb + j]);
  }
  frag_ab pv;
  #pragma unroll
  for (int j = 0; j < 8; ++j) pv[j] = (short)v[j];
  *(frag_ab*)((char*)wq + ((size_t)f << 10) + (size_t)(L << 4)) = pv;
}

// ---------------------------------------------------------------------------
// Prologue 2: zero the counters (d_ws poisoned each launch).
// ---------------------------------------------------------------------------
__global__ __launch_bounds__(256) void clear_cnt(uint32_t* __restrict__ c) {
  int i = blockIdx.x * 256 + threadIdx.x;
  if (i < 3072) c[i] = 0;
}

// ---------------------------------------------------------------------------
// 3-stage pipeline: A (layer0) -> B (h1 @ W_ih1^T) -> C (h2 recurrence + FC).
// R9 schedule (930us verified: poll-overlap + xg swizzle) with two R10 deltas:
//  1. fast rcp in sigmoid/tanh (v_rcp_f32 vs ~10-op IEEE div) -- cuts the
//     serial gate-epilogue VALU in A and C by ~200 ops/thread/step.
//  2. trailing barrier after PUBLISH removed (all stages): since R9 moved
//     the consumer polls BEFORE the 2nd barrier, that barrier already
//     broadcasts the poll result to all waves; PUBLISH visibility ordering
//     comes from the drain-before-barrier, not the trailing barrier.
//     2 barriers/step instead of 3.
// ---------------------------------------------------------------------------
__global__ __launch_bounds__(1024) void gru_pipe(
    const float* __restrict__ x,
    const float* __restrict__ bih0, const float* __restrict__ bhh0,
    const float* __restrict__ bih1, const float* __restrict__ bhh1,
    const float* __restrict__ fcw,  const float* __restrict__ fcb,
    char* __restrict__ ws,
    float* __restrict__ out)
{
  __shared__ __align__(16) char smem[82944];   // 81 KB -> 1 block/CU

  const int tid  = threadIdx.x;
  const int wave = tid >> 6;
  const int lane = tid & 63;
  const int q    = lane >> 4;
  const int c16  = lane & 15;
  const int bid  = blockIdx.x;
  const uint32_t lane16 = (uint32_t)(lane << 4);
  int dead = 0;

#define BARRIER() asm volatile("s_waitcnt lgkmcnt(0)\n\ts_barrier" ::: "memory")
#define ISSUE3(sl, oR, oZ, oN)                                              \
  asm volatile("global_load_dwordx4 %0, %3, %6\n\t"                         \
               "global_load_dwordx4 %1, %4, %6\n\t"                         \
               "global_load_dwordx4 %2, %5, %6"                             \
               : "=&v"(rr_[sl]), "=&v"(rz_[sl]), "=&v"(rn_[sl])             \
               : "v"((uint32_t)(oR)), "v"((uint32_t)(oZ)),                  \
                 "v"((uint32_t)(oN)), "s"(ws)                               \
               : "memory")
#define WAIT3(sl, NSTR)                                                     \
  asm volatile("s_waitcnt vmcnt(" NSTR ")"                                  \
               : "+v"(rr_[sl]), "+v"(rz_[sl]), "+v"(rn_[sl]) :: "memory")
#define SCLOAD4(dst, off)                                                   \
  asm volatile("global_load_dwordx4 %0, %1, %2 sc0 sc1"                     \
               : "=&v"(dst) : "v"((uint32_t)(off)), "s"(ws) : "memory")
#define SCSTORE4(off, val)                                                  \
  asm volatile("global_store_dwordx4 %0, %1, %2 sc0 sc1"                    \
               :: "v"((uint32_t)(off)), "v"(val), "s"(ws) : "memory")
#define SCSTORE2(off, val)                                                  \
  asm volatile("global_store_dwordx2 %0, %1, %2 sc0 sc1"                    \
               :: "v"((uint32_t)(off)), "v"(val), "s"(ws) : "memory")
#define PUBLISH(off, val)                                                   \
  asm volatile("global_store_dword %0, %1, %2 sc0 sc1"                      \
               :: "v"((uint32_t)(off)), "v"((uint32_t)(val)), "s"(ws)       \
               : "memory")
#define POLL(off, target)                                                   \
  do {                                                                      \
    int tgt = (target);                                                     \
    if (tgt > 0) {                                                          \
      int it = 0, bound = dead ? 64 : (1 << 17);                            \
      for (;;) {                                                            \
        uint32_t v_;                                                        \
        asm volatile("global_load_dword %0, %1, %2 sc0 sc1\n\t"             \
                     "s_waitcnt vmcnt(0)"                                   \
                     : "=&v"(v_) : "v"((uint32_t)(off)), "s"(ws)            \
                     : "memory");                                           \
        if ((int)v_ >= tgt) break;                                          \
        if (++it >= bound) { dead = 1; break; }                             \
        __builtin_amdgcn_s_sleep(2);                                        \
      }                                                                     \
    }                                                                       \
  } while (0)

  // =========================================================================
  if (bid < 64) {
    // ----------------------------- Stage A: layer 0 -----------------------
    const int g = bid, row0 = g * 32;
    unsigned short (*h1b)[264] = (unsigned short (*)[264])smem;       // [2*32][264]
    unsigned short (*xs)[32]   = (unsigned short (*)[32])(smem + 33792); // [2*32][32]
    for (int i = tid; i < 2 * 32 * 264; i += 1024) ((unsigned short*)smem)[i] = 0;
    for (int i = tid; i < 2 * 32 * 32; i += 1024) ((unsigned short*)(smem + 33792))[i] = 0;
    const int c = wave * 16 + c16;
    const float brc = bih0[c] + bhh0[c];
    const float bzc = bih0[HID + c] + bhh0[HID + c];
    const float bni = bih0[2 * HID + c];
    const float bnh = bhh0[2 * HID + c];
    {  // x(0)
      int r = tid & 31, cc = tid >> 5;
      float xv = x[(size_t)(row0 + r) * IN_DIM + (cc < 18 ? cc : 17)];
      if (cc < 18) xs[r][cc] = f2bf(xv);
    }
    __syncthreads();

    const uint32_t b0r = (uint32_t)((wave * KT0) << 10);
    const uint32_t b0z = (uint32_t)(((16 + wave) * KT0) << 10);
    const uint32_t b0n = (uint32_t)(((32 + wave) * KT0) << 10);
    frag_ab rr_[3], rz_[3], rn_[3];
    float h1m[2][4] = {{0, 0, 0, 0}, {0, 0, 0, 0}};
    uint32_t xvu = 0;
    #pragma unroll
    for (int i = 0; i < 3; ++i)
      ISSUE3(i, b0r + i * 1024 + lane16, b0z + i * 1024 + lane16,
                b0n + i * 1024 + lane16);

    for (int t = 0; t < T_STEPS; ++t) {
      const int p = t & 1, pn = p ^ 1;
      {  // x(t+1) prefetch (plain cached load)
        int t1 = (t + 1 < T_STEPS) ? t + 1 : T_STEPS - 1;
        int r = tid & 31, cc = tid >> 5;
        uint32_t xo = (uint32_t)((((t1 * BATCH) + row0 + r) * IN_DIM +
                                  (cc < 18 ? cc : 17)) * 4);
        asm volatile("global_load_dword %0, %1, %2"
                     : "=&v"(xvu) : "v"(xo), "s"(x) : "memory");
      }
      f32x4 a_r[2] = {{0,0,0,0},{0,0,0,0}}, a_z[2] = {{0,0,0,0},{0,0,0,0}};
      f32x4 a_nx[2] = {{0,0,0,0},{0,0,0,0}}, a_nh[2] = {{0,0,0,0},{0,0,0,0}};
      #pragma unroll
      for (int i = 0; i < KT0; ++i) {
        const int sl = i % 3;
        WAIT3(sl, "6");
        frag_ab A0, A1v;
        if (i == 0) {
          A0  = *(const frag_ab*)&xs[p * 32 + c16][q * 8];
          A1v = *(const frag_ab*)&xs[p * 32 + 16 + c16][q * 8];
        } else {
          A0  = *(const frag_ab*)&h1b[p * 32 + c16][(i - 1) * 32 + q * 8];
          A1v = *(const frag_ab*)&h1b[p * 32 + 16 + c16][(i - 1) * 32 + q * 8];
        }
        a_r[0] = mfma16(A0, rr_[sl], a_r[0]);  a_r[1] = mfma16(A1v, rr_[sl], a_r[1]);
        a_z[0] = mfma16(A0, rz_[sl], a_z[0]);  a_z[1] = mfma16(A1v, rz_[sl], a_z[1]);
        if (i == 0) { a_nx[0] = mfma16(A0, rn_[sl], a_nx[0]);
                      a_nx[1] = mfma16(A1v, rn_[sl], a_nx[1]); }
        else        { a_nh[0] = mfma16(A0, rn_[sl], a_nh[0]);
                      a_nh[1] = mfma16(A1v, rn_[sl], a_nh[1]); }
        const int nk = (i + 3) % KT0;
        ISSUE3(sl, b0r + nk * 1024 + lane16, b0z + nk * 1024 + lane16,
                   b0n + nk * 1024 + lane16);
      }
      // epilogue: x(t+1) stage + h1 update
      { int r = tid & 31, cc = tid >> 5;
        if (cc < 18) xs[pn * 32 + r][cc] = f2bf(__uint_as_float(xvu)); }
      #pragma unroll
      for (int mt = 0; mt < 2; ++mt)
        #pragma unroll
        for (int rrI = 0; rrI < 4; ++rrI) {
          const int row = mt * 16 + q * 4 + rrI;
          float rg = sigmoidf_(a_r[mt][rrI] + brc);
          float zg = sigmoidf_(a_z[mt][rrI] + bzc);
          float ng = tanhf_(a_nx[mt][rrI] + bni + rg * (a_nh[mt][rrI] + bnh));
          float hn = (1.f - zg) * ng + zg * h1m[mt][rrI];
          h1m[mt][rrI] = hn;
          h1b[pn * 32 + row][c] = f2bf(hn);
        }
      BARRIER();
      {  // export frag j = wave (A-operand layout for B)
        const int mt = wave >> 3, kt = wave & 7;
        frag_ab fa = *(const frag_ab*)&h1b[pn * 32 + mt * 16 + c16][kt * 32 + q * 8];
        SCSTORE4(H1SLOT(t, g) + (uint32_t)(wave * 1024 + lane * 16), fa);
      }
      // poll-overlap (R9): tid0's poll RTT rides the export drain.
      if (tid == 0) POLL(CNTB(g), t - 3);
      asm volatile("s_waitcnt vmcnt(0)" ::: "memory");
      BARRIER();
      if (tid == 0) PUBLISH(CNTA(g), t + 1);
      // trailing barrier removed (R10): poll already broadcast by the
      // barrier above; publish is fire-and-forget.
    }

  } else if (bid < 128) {
    // ------------------------ Stage B: xg1 = h1 @ W_ih1^T -----------------
    const int g = bid - 64;
    unsigned short* slab = (unsigned short*)smem;   // [2][16384 B] frag slabs
    const int c = wave * 16 + c16;
    const float bri = bih1[c], bzi = bih1[HID + c], bni = bih1[2 * HID + c];
    const uint32_t b1r = (uint32_t)((L0_FRAGS + wave * KT1) << 10);
    const uint32_t b1z = (uint32_t)((L0_FRAGS + (16 + wave) * KT1) << 10);
    const uint32_t b1n = (uint32_t)((L0_FRAGS + (32 + wave) * KT1) << 10);
    frag_ab rr_[4], rz_[4], rn_[4];
    #pragma unroll
    for (int i = 0; i < 4; ++i)
      ISSUE3(i, b1r + i * 1024 + lane16, b1z + i * 1024 + lane16,
                b1n + i * 1024 + lane16);

    if (tid == 0) POLL(CNTA(g), 1);
    BARRIER();
    { uint4v u; SCLOAD4(u, H1SLOT(0, g) + tid * 16);
      asm volatile("s_waitcnt vmcnt(0)" : "+v"(u) :: "memory");
      *(uint4v*)((char*)slab + tid * 16) = u; }
    if (tid == 0) POLL(CNTA(g), 2);
    __syncthreads();

    for (int t = 0; t < T_STEPS; ++t) {
      const int p = t & 1, pn = p ^ 1;
      uint4v stg = {0, 0, 0, 0};
      const bool hasst = (t + 1 < T_STEPS);
      if (hasst) SCLOAD4(stg, H1SLOT(t + 1, g) + tid * 16);
      f32x4 acc[3][2];
      #pragma unroll
      for (int ga = 0; ga < 3; ++ga) { acc[ga][0] = (f32x4){0,0,0,0};
                                       acc[ga][1] = (f32x4){0,0,0,0}; }
      #pragma unroll
      for (int i = 0; i < 8; ++i) {
        const int sl = i & 3;
        WAIT3(sl, "9");
        frag_ab A0  = *(const frag_ab*)((char*)slab + p * 16384 + (i * 64 + lane) * 16);
        frag_ab A1v = *(const frag_ab*)((char*)slab + p * 16384 + ((8 + i) * 64 + lane) * 16);
        acc[0][0] = mfma16(A0, rr_[sl], acc[0][0]); acc[0][1] = mfma16(A1v, rr_[sl], acc[0][1]);
        acc[1][0] = mfma16(A0, rz_[sl], acc[1][0]); acc[1][1] = mfma16(A1v, rz_[sl], acc[1][1]);
        acc[2][0] = mfma16(A0, rn_[sl], acc[2][0]); acc[2][1] = mfma16(A1v, rn_[sl], acc[2][1]);
        const int nk = (i + 4) & 7;
        ISSUE3(sl, b1r + nk * 1024 + lane16, b1z + nk * 1024 + lane16,
                   b1n + nk * 1024 + lane16);
      }
      if (hasst) *(uint4v*)((char*)slab + pn * 16384 + tid * 16) = stg;
      #pragma unroll
      for (int ga = 0; ga < 3; ++ga) {
        const float bb = (ga == 0) ? bri : (ga == 1) ? bzi : bni;
        const int col = ga * 256 + c;
        #pragma unroll
        for (int mt = 0; mt < 2; ++mt) {
          uint2v u;
          u[0] = (uint32_t)f2bf(acc[ga][mt][0] + bb) |
                 ((uint32_t)f2bf(acc[ga][mt][1] + bb) << 16);
          u[1] = (uint32_t)f2bf(acc[ga][mt][2] + bb) |
                 ((uint32_t)f2bf(acc[ga][mt][3] + bb) << 16);
          SCSTORE2(XGSLOT(t, g) + XGOFFS(col, (mt * 16 + q * 4) * 2), u);
        }
      }
      // poll-overlap (R9): polls ride the export drain.
      if (tid == 0) {
        if (t <= 125) POLL(CNTA(g), t + 3);
        POLL(CNTC(g), t - 3);
      }
      asm volatile("s_waitcnt vmcnt(0)" ::: "memory");
      BARRIER();
      if (tid == 0) PUBLISH(CNTB(g), t + 1);
      // trailing barrier removed (R10)
    }

  } else {
    // ---------------- Stage C: h2 recurrence (W_hh1) + gates + FC ---------
    const int g = bid - 128, row0 = g * 32;
    unsigned short* xg = (unsigned short*)smem;                       // 48 KB
    unsigned short (*h2b)[264] = (unsigned short (*)[264])(smem + 49152);
    for (int i = tid; i < 2 * 32 * 264; i += 1024)
      ((unsigned short*)(smem + 49152))[i] = 0;
    const int c = wave * 16 + c16;
    const float brh = bhh1[c], bzh = bhh1[HID + c], bnh = bhh1[2 * HID + c];
    const uint32_t bCr = (uint32_t)((L0_FRAGS + wave * KT1 + 8) << 10);
    const uint32_t bCz = (uint32_t)((L0_FRAGS + (16 + wave) * KT1 + 8) << 10);
    const uint32_t bCn = (uint32_t)((L0_FRAGS + (32 + wave) * KT1 + 8) << 10);
    frag_ab rr_[4], rz_[4], rn_[4];
    float h2m[2][4] = {{0, 0, 0, 0}, {0, 0, 0, 0}};
    #pragma unroll
    for (int i = 0; i < 4; ++i)
      ISSUE3(i, bCr + i * 1024 + lane16, bCz + i * 1024 + lane16,
                bCn + i * 1024 + lane16);

    if (tid == 0) POLL(CNTB(g), 1);
    BARRIER();
    { uint4v u0, u1, u2;
      SCLOAD4(u0, XGSLOT(0, g) + tid * 16);
      SCLOAD4(u1, XGSLOT(0, g) + 16384 + tid * 16);
      SCLOAD4(u2, XGSLOT(0, g) + 32768 + tid * 16);
      asm volatile("s_waitcnt vmcnt(0)" : "+v"(u0), "+v"(u1), "+v"(u2) :: "memory");
      *(uint4v*)((char*)xg + tid * 16) = u0;
      *(uint4v*)((char*)xg + 16384 + tid * 16) = u1;
      *(uint4v*)((char*)xg + 32768 + tid * 16) = u2; }
    if (tid == 0) POLL(CNTB(g), 2);
    __syncthreads();

    for (int t = 0; t < T_STEPS; ++t) {
      const int p = t & 1, pn = p ^ 1;
      uint4v s0 = {0,0,0,0}, s1 = {0,0,0,0}, s2 = {0,0,0,0};
      const bool hasst = (t + 1 < T_STEPS);
      if (hasst) {
        SCLOAD4(s0, XGSLOT(t + 1, g) + tid * 16);
        SCLOAD4(s1, XGSLOT(t + 1, g) + 16384 + tid * 16);
        SCLOAD4(s2, XGSLOT(t + 1, g) + 32768 + tid * 16);
      }
      f32x4 acc[3][2];
      #pragma unroll
      for (int ga = 0; ga < 3; ++ga) { acc[ga][0] = (f32x4){0,0,0,0};
                                       acc[ga][1] = (f32x4){0,0,0,0}; }
      #pragma unroll
      for (int i = 0; i < 8; ++i) {
        const int sl = i & 3;
        WAIT3(sl, "9");
        frag_ab A0  = *(const frag_ab*)&h2b[p * 32 + c16][i * 32 + q * 8];
        frag_ab A1v = *(const frag_ab*)&h2b[p * 32 + 16 + c16][i * 32 + q * 8];
        acc[0][0] = mfma16(A0, rr_[sl], acc[0][0]); acc[0][1] = mfma16(A1v, rr_[sl], acc[0][1]);
        acc[1][0] = mfma16(A0, rz_[sl], acc[1][0]); acc[1][1] = mfma16(A1v, rz_[sl], acc[1][1]);
        acc[2][0] = mfma16(A0, rn_[sl], acc[2][0]); acc[2][1] = mfma16(A1v, rn_[sl], acc[2][1]);
        const int nk = (i + 4) & 7;
        ISSUE3(sl, bCr + nk * 1024 + lane16, bCz + nk * 1024 + lane16,
                   bCn + nk * 1024 + lane16);
      }
      // epilogue: read xg(t) from LDS (swizzled), gates, h2 update
      #pragma unroll
      for (int mt = 0; mt < 2; ++mt) {
        uint2v ur = *(const uint2v*)((char*)xg + XGOFFS(0 * 256 + c, (mt * 16 + q * 4) * 2));
        uint2v uz = *(const uint2v*)((char*)xg + XGOFFS(1 * 256 + c, (mt * 16 + q * 4) * 2));
        uint2v un = *(const uint2v*)((char*)xg + XGOFFS(2 * 256 + c, (mt * 16 + q * 4) * 2));
        #pragma unroll
        for (int rrI = 0; rrI < 4; ++rrI) {
          const int row = mt * 16 + q * 4 + rrI;
          const uint32_t wr = (rrI < 2) ? ur[0] : ur[1];
          const uint32_t wz = (rrI < 2) ? uz[0] : uz[1];
          const uint32_t wn = (rrI < 2) ? un[0] : un[1];
          const int sh = (rrI & 1) * 16;
          float xr = bf2f((unsigned short)(wr >> sh));
          float xz = bf2f((unsigned short)(wz >> sh));
          float xn = bf2f((unsigned short)(wn >> sh));
          float rg = sigmoidf_(xr + acc[0][mt][rrI] + brh);
          float zg = sigmoidf_(xz + acc[1][mt][rrI] + bzh);
          float ng = tanhf_(xn + rg * (acc[2][mt][rrI] + bnh));
          float hn = (1.f - zg) * ng + zg * h2m[mt][rrI];
          h2m[mt][rrI] = hn;
          h2b[pn * 32 + row][c] = f2bf(hn);
        }
      }
      BARRIER();   // all xg(t) reads done before overwrite
      // poll-overlap (R9): tid0's poll rides the staging drains.
      if (tid == 0 && t <= 125) POLL(CNTB(g), t + 3);
      if (hasst) {
        asm volatile("s_waitcnt vmcnt(0)" : "+v"(s0), "+v"(s1), "+v"(s2) :: "memory");
        *(uint4v*)((char*)xg + tid * 16) = s0;
        *(uint4v*)((char*)xg + 16384 + tid * 16) = s1;
        *(uint4v*)((char*)xg + 32768 + tid * 16) = s2;
      }
      BARRIER();
      if (tid == 0) PUBLISH(CNTC(g), t + 1);
      // trailing barrier removed (R10)
    }

    // FC head from h2b parity 0 (h2(127): pn of t=127 is 0).
    // h2b writes at t=127 precede that step's first BARRIER -> visible here.
    if (tid < 128) {
      const int row = tid >> 2, o = tid & 3;
      float acc2 = fcb[o];
      #pragma unroll 8
      for (int k = 0; k < HID; ++k)
        acc2 += bf2f(h2b[row][k]) * fcw[o * HID + k];
      float sg = sigmoidf_(acc2);
      out[(size_t)(row0 + row) * 4 + o] = sg * 2.f - 1.f;
    }
  }
#undef BARRIER
#undef ISSUE3
#undef WAIT3
#undef SCLOAD4
#undef SCSTORE4
#undef SCSTORE2
#undef PUBLISH
#undef POLL
}

extern "C" void kernel_launch(void* const* d_in, const int* in_sizes, int n_in,
                              void* d_out, int out_size, void* d_ws, size_t ws_size,
                              hipStream_t stream) {
  const float* x    = (const float*)d_in[0];
  const float* Wih0 = (const float*)d_in[1];
  const float* Whh0 = (const float*)d_in[2];
  const float* bih0 = (const float*)d_in[3];
  const float* bhh0 = (const float*)d_in[4];
  const float* Wih1 = (const float*)d_in[5];
  const float* Whh1 = (const float*)d_in[6];
  const float* bih1 = (const float*)d_in[7];
  const float* bhh1 = (const float*)d_in[8];
  const float* fcw  = (const float*)d_in[9];
  const float* fcb  = (const float*)d_in[10];

  unsigned short* wq = (unsigned short*)d_ws;
  uint32_t* cnt = (uint32_t*)((char*)d_ws + CNT_OFF);

  repack_w<<<(TOT_FRAGS * 64 + 255) / 256, 256, 0, stream>>>(Wih0, Whh0, Wih1, Whh1, wq);
  clear_cnt<<<12, 256, 0, stream>>>(cnt);
  gru_pipe<<<192, 1024, 0, stream>>>(x, bih0, bhh0, bih1, bhh1, fcw, fcb,
                                     (char*)d_ws, (float*)d_out);
}

// Round 12
// 786.688 us; speedup vs baseline: 1.5834x; 1.0215x over previous
//
#include <hip/hip_runtime.h>
#include <hip/hip_bf16.h>
#include <stdint.h>

// Problem constants
#define T_STEPS 128
#define BATCH   2048
#define IN_DIM  18
#define HID     256

// Fragment repack (same layout as R3)
#define NT   48
#define KT0  9
#define KT1  16
#define L0_FRAGS 432
#define L1_FRAGS 768
#define TOT_FRAGS 1200

// d_ws layout (total need ~17.7 MB)
#define CNT_OFF  1310720u
#define CNTA(g)  (CNT_OFF + (uint32_t)(g) * 64u)
#define CNTB(g)  (CNT_OFF + 4096u + (uint32_t)(g) * 64u)
#define CNTC(g)  (CNT_OFF + 8192u + (uint32_t)(g) * 64u)
#define H1_OFF   1441792u
#define H1SLOT(t, g) (H1_OFF + (uint32_t)(((((t) & 3) * 64) + (g)) * 16384))
#define XG_OFF   5898240u
#define XGSLOT(t, g) (XG_OFF + (uint32_t)(((((t) & 3) * 64) + (g)) * 49152))

// xg layout inside a slot: col-major 64B rows, XOR-swizzled (R9/R10 verified).
#define XGOFFS(col, inner) ((uint32_t)((col) * 64 + ((inner) ^ (((col) & 7) << 3))))

using frag_ab = __attribute__((ext_vector_type(8))) short;
using f32x4   = __attribute__((ext_vector_type(4))) float;
using uint4v  = __attribute__((ext_vector_type(4))) unsigned int;
using uint2v  = __attribute__((ext_vector_type(2))) unsigned int;

// R12: round-half-up bf16 conversion (2 VALU ops vs 5 for RNE; differs from
// RNE only on exact 0x8000 ties -- absmax margin is 4x).
__device__ __forceinline__ unsigned short f2bf(float f) {
  return (unsigned short)((__float_as_uint(f) + 0x8000u) >> 16);
}
__device__ __forceinline__ float bf2f(unsigned short v) {
  return __uint_as_float((uint32_t)v << 16);
}
// R10: raw v_rcp_f32 (~1 ulp) instead of IEEE div sequence.
__device__ __forceinline__ float sigmoidf_(float v) {
  return __builtin_amdgcn_rcpf(1.f + __expf(-v));
}
__device__ __forceinline__ float tanhf_(float v) {
  float a = fabsf(v);
  float e = __expf(-2.f * a);
  float r = (1.f - e) * __builtin_amdgcn_rcpf(1.f + e);
  return v < 0.f ? -r : r;
}
__device__ __forceinline__ f32x4 mfma16(frag_ab a, frag_ab b, f32x4 c) {
  return __builtin_amdgcn_mfma_f32_16x16x32_bf16(a, b, c, 0, 0, 0);
}

// ---------------------------------------------------------------------------
// Prologue 1: fp32 weights -> bf16 MFMA B-fragments (layout as R3).
// ---------------------------------------------------------------------------
__global__ __launch_bounds__(256) void repack_w(
    const float* __restrict__ Wih0, const float* __restrict__ Whh0,
    const float* __restrict__ Wih1, const float* __restrict__ Whh1,
    unsigned short* __restrict__ wq)
{
  int g = blockIdx.x * 256 + threadIdx.x;
  if (g >= TOT_FRAGS * 64) return;
  int f = g >> 6;
  int L = g & 63;
  int q = L >> 4, c16 = L & 15;
  unsigned short v[8];
  if (f < L0_FRAGS) {
    int n = f / KT0, kt = f - n * KT0;
    int col = n * 16 + c16;
    if (kt == 0) {
      #pragma unroll
      for (int j = 0; j < 8; ++j) {
        int k = q * 8 + j;
        v[j] = (k < IN_DIM) ? f2bf(Wih0[col * IN_DIM + k]) : (unsigned short)0;
      }
    } else {
      int kb = (kt - 1) * 32 + q * 8;
      #pragma unroll
      for (int j = 0; j < 8; ++j) v[j] = f2bf(Whh0[col * HID + kb + j]);
    }
  } else {
    int f1 = f - L0_FRAGS;
    int n = f1 / KT1, kt = f1 - n * KT1;
    int col = n * 16 + c16;
    const float* __restrict__ W = (kt < 8) ? Wih1 : Whh1;
    int kb = (kt & 7) * 32 + q * 8;
    #pragma unroll
    for (int j = 0; j < 8; ++j) v[j] = f2bf(W[col * HID + kb + j]);
  }
  frag_ab pv;
  #pragma unroll
  for (int j = 0; j < 8; ++j) pv[j] = (short)v[j];
  *(frag_ab*)((char*)wq + ((size_t)f << 10) + (size_t)(L << 4)) = pv;
}

// ---------------------------------------------------------------------------
// Prologue 2: zero the counters (d_ws poisoned each launch).
// ---------------------------------------------------------------------------
__global__ __launch_bounds__(256) void clear_cnt(uint32_t* __restrict__ c) {
  int i = blockIdx.x * 256 + threadIdx.x;
  if (i < 3072) c[i] = 0;
}

// ---------------------------------------------------------------------------
// 3-stage pipeline: A (layer0) -> B (h1 @ W_ih1^T) -> C (h2 recurrence + FC).
// R10 schedule (803us verified) + R12 deltas:
//  1. fast f2bf (round-half-up, 2 ops).
//  2. resident weights in STAGE B ONLY (register budget: B ~110 <= 128;
//     A would overflow at ~132 -- the root cause of R5/R11 NaNs -- and C is
//     marginal at ~122, so both stay R10-verbatim). B: ktiles 0-1 resident
//     (24 VGPR, stream 384->288 KB/step); streamed ktiles 2-7 in 3 slots,
//     TIED waits at every js ("9,9,9,6,6,6"); prologue waits TIED in
//     3-frag groups (the proven WAIT3 shape; no untied drains anywhere).
//  3. __launch_bounds__(1024,4): allocator targets 4 waves/EU (cap 128)
//     instead of squeezing to 64 with spills.
// Queue walk (B, steady): top=[stg]=1; js0-2 waits vacuous (slot data
// drained at prev step end); js3 "6" retires stg+kt5; js4/5 retire kt6/kt7;
// end-of-step drain clears the 9 prefetches. t=0 and t=127 walked equal.
// ---------------------------------------------------------------------------
__global__ __launch_bounds__(1024, 4) void gru_pipe(
    const float* __restrict__ x,
    const float* __restrict__ bih0, const float* __restrict__ bhh0,
    const float* __restrict__ bih1, const float* __restrict__ bhh1,
    const float* __restrict__ fcw,  const float* __restrict__ fcb,
    char* __restrict__ ws,
    float* __restrict__ out)
{
  __shared__ __align__(16) char smem[82944];   // 81 KB -> 1 block/CU

  const int tid  = threadIdx.x;
  const int wave = tid >> 6;
  const int lane = tid & 63;
  const int q    = lane >> 4;
  const int c16  = lane & 15;
  const int bid  = blockIdx.x;
  const uint32_t lane16 = (uint32_t)(lane << 4);
  int dead = 0;

#define BARRIER() asm volatile("s_waitcnt lgkmcnt(0)\n\ts_barrier" ::: "memory")
#define ISSUE3(sl, oR, oZ, oN)                                              \
  asm volatile("global_load_dwordx4 %0, %3, %6\n\t"                         \
               "global_load_dwordx4 %1, %4, %6\n\t"                         \
               "global_load_dwordx4 %2, %5, %6"                             \
               : "=&v"(rr_[sl]), "=&v"(rz_[sl]), "=&v"(rn_[sl])             \
               : "v"((uint32_t)(oR)), "v"((uint32_t)(oZ)),                  \
                 "v"((uint32_t)(oN)), "s"(ws)                               \
               : "memory")
#define WAIT3(sl, NSTR)                                                     \
  asm volatile("s_waitcnt vmcnt(" NSTR ")"                                  \
               : "+v"(rr_[sl]), "+v"(rz_[sl]), "+v"(rn_[sl]) :: "memory")
#define RESLOAD(dst, off)                                                   \
  asm volatile("global_load_dwordx4 %0, %1, %2"                             \
               : "=&v"(dst) : "v"((uint32_t)(off)), "s"(ws) : "memory")
#define SCLOAD4(dst, off)                                                   \
  asm volatile("global_load_dwordx4 %0, %1, %2 sc0 sc1"                     \
               : "=&v"(dst) : "v"((uint32_t)(off)), "s"(ws) : "memory")
#define SCSTORE4(off, val)                                                  \
  asm volatile("global_store_dwordx4 %0, %1, %2 sc0 sc1"                    \
               :: "v"((uint32_t)(off)), "v"(val), "s"(ws) : "memory")
#define SCSTORE2(off, val)                                                  \
  asm volatile("global_store_dwordx2 %0, %1, %2 sc0 sc1"                    \
               :: "v"((uint32_t)(off)), "v"(val), "s"(ws) : "memory")
#define PUBLISH(off, val)                                                   \
  asm volatile("global_store_dword %0, %1, %2 sc0 sc1"                      \
               :: "v"((uint32_t)(off)), "v"((uint32_t)(val)), "s"(ws)       \
               : "memory")
#define POLL(off, target)                                                   \
  do {                                                                      \
    int tgt = (target);                                                     \
    if (tgt > 0) {                                                          \
      int it = 0, bound = dead ? 64 : (1 << 17);                            \
      for (;;) {                                                            \
        uint32_t v_;                                                        \
        asm volatile("global_load_dword %0, %1, %2 sc0 sc1\n\t"             \
                     "s_waitcnt vmcnt(0)"                                   \
                     : "=&v"(v_) : "v"((uint32_t)(off)), "s"(ws)            \
                     : "memory");                                           \
        if ((int)v_ >= tgt) break;                                          \
        if (++it >= bound) { dead = 1; break; }                             \
        __builtin_amdgcn_s_sleep(2);                                        \
      }                                                                     \
    }                                                                       \
  } while (0)

  // =========================================================================
  if (bid < 64) {
    // ---------------- Stage A: layer 0 (R10 verbatim) ---------------------
    const int g = bid, row0 = g * 32;
    unsigned short (*h1b)[264] = (unsigned short (*)[264])smem;       // [2*32][264]
    unsigned short (*xs)[32]   = (unsigned short (*)[32])(smem + 33792); // [2*32][32]
    for (int i = tid; i < 2 * 32 * 264; i += 1024) ((unsigned short*)smem)[i] = 0;
    for (int i = tid; i < 2 * 32 * 32; i += 1024) ((unsigned short*)(smem + 33792))[i] = 0;
    const int c = wave * 16 + c16;
    const float brc = bih0[c] + bhh0[c];
    const float bzc = bih0[HID + c] + bhh0[HID + c];
    const float bni = bih0[2 * HID + c];
    const float bnh = bhh0[2 * HID + c];
    {  // x(0)
      int r = tid & 31, cc = tid >> 5;
      float xv = x[(size_t)(row0 + r) * IN_DIM + (cc < 18 ? cc : 17)];
      if (cc < 18) xs[r][cc] = f2bf(xv);
    }
    __syncthreads();

    const uint32_t b0r = (uint32_t)((wave * KT0) << 10);
    const uint32_t b0z = (uint32_t)(((16 + wave) * KT0) << 10);
    const uint32_t b0n = (uint32_t)(((32 + wave) * KT0) << 10);
    frag_ab rr_[3], rz_[3], rn_[3];
    float h1m[2][4] = {{0, 0, 0, 0}, {0, 0, 0, 0}};
    uint32_t xvu = 0;
    #pragma unroll
    for (int i = 0; i < 3; ++i)
      ISSUE3(i, b0r + i * 1024 + lane16, b0z + i * 1024 + lane16,
                b0n + i * 1024 + lane16);

    for (int t = 0; t < T_STEPS; ++t) {
      const int p = t & 1, pn = p ^ 1;
      {  // x(t+1) prefetch (plain cached load)
        int t1 = (t + 1 < T_STEPS) ? t + 1 : T_STEPS - 1;
        int r = tid & 31, cc = tid >> 5;
        uint32_t xo = (uint32_t)((((t1 * BATCH) + row0 + r) * IN_DIM +
                                  (cc < 18 ? cc : 17)) * 4);
        asm volatile("global_load_dword %0, %1, %2"
                     : "=&v"(xvu) : "v"(xo), "s"(x) : "memory");
      }
      f32x4 a_r[2] = {{0,0,0,0},{0,0,0,0}}, a_z[2] = {{0,0,0,0},{0,0,0,0}};
      f32x4 a_nx[2] = {{0,0,0,0},{0,0,0,0}}, a_nh[2] = {{0,0,0,0},{0,0,0,0}};
      #pragma unroll
      for (int i = 0; i < KT0; ++i) {
        const int sl = i % 3;
        WAIT3(sl, "6");
        frag_ab A0, A1v;
        if (i == 0) {
          A0  = *(const frag_ab*)&xs[p * 32 + c16][q * 8];
          A1v = *(const frag_ab*)&xs[p * 32 + 16 + c16][q * 8];
        } else {
          A0  = *(const frag_ab*)&h1b[p * 32 + c16][(i - 1) * 32 + q * 8];
          A1v = *(const frag_ab*)&h1b[p * 32 + 16 + c16][(i - 1) * 32 + q * 8];
        }
        a_r[0] = mfma16(A0, rr_[sl], a_r[0]);  a_r[1] = mfma16(A1v, rr_[sl], a_r[1]);
        a_z[0] = mfma16(A0, rz_[sl], a_z[0]);  a_z[1] = mfma16(A1v, rz_[sl], a_z[1]);
        if (i == 0) { a_nx[0] = mfma16(A0, rn_[sl], a_nx[0]);
                      a_nx[1] = mfma16(A1v, rn_[sl], a_nx[1]); }
        else        { a_nh[0] = mfma16(A0, rn_[sl], a_nh[0]);
                      a_nh[1] = mfma16(A1v, rn_[sl], a_nh[1]); }
        const int nk = (i + 3) % KT0;
        ISSUE3(sl, b0r + nk * 1024 + lane16, b0z + nk * 1024 + lane16,
                   b0n + nk * 1024 + lane16);
      }
      // epilogue: x(t+1) stage + h1 update
      { int r = tid & 31, cc = tid >> 5;
        if (cc < 18) xs[pn * 32 + r][cc] = f2bf(__uint_as_float(xvu)); }
      #pragma unroll
      for (int mt = 0; mt < 2; ++mt)
        #pragma unroll
        for (int rrI = 0; rrI < 4; ++rrI) {
          const int row = mt * 16 + q * 4 + rrI;
          float rg = sigmoidf_(a_r[mt][rrI] + brc);
          float zg = sigmoidf_(a_z[mt][rrI] + bzc);
          float ng = tanhf_(a_nx[mt][rrI] + bni + rg * (a_nh[mt][rrI] + bnh));
          float hn = (1.f - zg) * ng + zg * h1m[mt][rrI];
          h1m[mt][rrI] = hn;
          h1b[pn * 32 + row][c] = f2bf(hn);
        }
      BARRIER();
      {  // export frag j = wave (A-operand layout for B)
        const int mt = wave >> 3, kt = wave & 7;
        frag_ab fa = *(const frag_ab*)&h1b[pn * 32 + mt * 16 + c16][kt * 32 + q * 8];
        SCSTORE4(H1SLOT(t, g) + (uint32_t)(wave * 1024 + lane * 16), fa);
      }
      // poll-overlap (R9): tid0's poll RTT rides the export drain.
      if (tid == 0) POLL(CNTB(g), t - 3);
      asm volatile("s_waitcnt vmcnt(0)" ::: "memory");
      BARRIER();
      if (tid == 0) PUBLISH(CNTA(g), t + 1);
      // trailing barrier removed (R10)
    }

  } else if (bid < 128) {
    // ------------- Stage B: xg1 = h1 @ W_ih1^T (R12 residents) ------------
    const int g = bid - 64;
    unsigned short* slab = (unsigned short*)smem;   // [2][16384 B] frag slabs
    const int c = wave * 16 + c16;
    const float bri = bih1[c], bzi = bih1[HID + c], bni = bih1[2 * HID + c];
    const uint32_t b1r = (uint32_t)((L0_FRAGS + wave * KT1) << 10);
    const uint32_t b1z = (uint32_t)((L0_FRAGS + (16 + wave) * KT1) << 10);
    const uint32_t b1n = (uint32_t)((L0_FRAGS + (32 + wave) * KT1) << 10);
    frag_ab rr_[3], rz_[3], rn_[3];   // streamed slots (ktiles 2..7)
    frag_ab w_r0, w_r1, w_z0, w_z1, w_n0, w_n1;   // resident ktiles 0..1
    RESLOAD(w_r0, b1r + 0 * 1024 + lane16);
    RESLOAD(w_r1, b1r + 1 * 1024 + lane16);
    RESLOAD(w_z0, b1z + 0 * 1024 + lane16);
    RESLOAD(w_z1, b1z + 1 * 1024 + lane16);
    RESLOAD(w_n0, b1n + 0 * 1024 + lane16);
    RESLOAD(w_n1, b1n + 1 * 1024 + lane16);
    // tied prologue waits, proven 3-frag granularity (no untied drains):
    asm volatile("s_waitcnt vmcnt(3)"
                 : "+v"(w_r0), "+v"(w_r1), "+v"(w_z0) :: "memory");
    asm volatile("s_waitcnt vmcnt(0)"
                 : "+v"(w_z1), "+v"(w_n0), "+v"(w_n1) :: "memory");
    __builtin_amdgcn_sched_barrier(0);
    ISSUE3(0, b1r + 2 * 1024 + lane16, b1z + 2 * 1024 + lane16, b1n + 2 * 1024 + lane16);
    ISSUE3(1, b1r + 3 * 1024 + lane16, b1z + 3 * 1024 + lane16, b1n + 3 * 1024 + lane16);
    ISSUE3(2, b1r + 4 * 1024 + lane16, b1z + 4 * 1024 + lane16, b1n + 4 * 1024 + lane16);

    if (tid == 0) POLL(CNTA(g), 1);
    BARRIER();
    { uint4v u; SCLOAD4(u, H1SLOT(0, g) + tid * 16);
      asm volatile("s_waitcnt vmcnt(0)" : "+v"(u) :: "memory");  // drains prefills too
      *(uint4v*)((char*)slab + tid * 16) = u; }
    if (tid == 0) POLL(CNTA(g), 2);
    __syncthreads();

    for (int t = 0; t < T_STEPS; ++t) {
      const int p = t & 1, pn = p ^ 1;
      uint4v stg = {0, 0, 0, 0};
      const bool hasst = (t + 1 < T_STEPS);
      if (hasst) SCLOAD4(stg, H1SLOT(t + 1, g) + tid * 16);
      f32x4 acc[3][2];
      #pragma unroll
      for (int ga = 0; ga < 3; ++ga) { acc[ga][0] = (f32x4){0,0,0,0};
                                       acc[ga][1] = (f32x4){0,0,0,0}; }
      // ---- streamed ktiles 2..7; tied waits "9,9,9,6,6,6" (stg at js3) ----
      #pragma unroll
      for (int js = 0; js < 6; ++js) {
        const int kt = 2 + js, sl = js % 3;
        if (js < 3) { WAIT3(sl, "9"); } else { WAIT3(sl, "6"); }
        frag_ab A0  = *(const frag_ab*)((char*)slab + p * 16384 + (kt * 64 + lane) * 16);
        frag_ab A1v = *(const frag_ab*)((char*)slab + p * 16384 + ((8 + kt) * 64 + lane) * 16);
        acc[0][0] = mfma16(A0, rr_[sl], acc[0][0]); acc[0][1] = mfma16(A1v, rr_[sl], acc[0][1]);
        acc[1][0] = mfma16(A0, rz_[sl], acc[1][0]); acc[1][1] = mfma16(A1v, rz_[sl], acc[1][1]);
        acc[2][0] = mfma16(A0, rn_[sl], acc[2][0]); acc[2][1] = mfma16(A1v, rn_[sl], acc[2][1]);
        const int ktn = (js < 3) ? kt + 3 : kt - 3;   // 5,6,7 then next 2,3,4
        ISSUE3(sl, b1r + ktn * 1024 + lane16, b1z + ktn * 1024 + lane16,
                   b1n + ktn * 1024 + lane16);
      }
      // ---- resident ktiles 0..1 (register B-operands, zero loads) ----
      {
        frag_ab A0  = *(const frag_ab*)((char*)slab + p * 16384 + (0 * 64 + lane) * 16);
        frag_ab A1v = *(const frag_ab*)((char*)slab + p * 16384 + (8 * 64 + lane) * 16);
        acc[0][0] = mfma16(A0, w_r0, acc[0][0]); acc[0][1] = mfma16(A1v, w_r0, acc[0][1]);
        acc[1][0] = mfma16(A0, w_z0, acc[1][0]); acc[1][1] = mfma16(A1v, w_z0, acc[1][1]);
        acc[2][0] = mfma16(A0, w_n0, acc[2][0]); acc[2][1] = mfma16(A1v, w_n0, acc[2][1]);
      }
      {
        frag_ab A0  = *(const frag_ab*)((char*)slab + p * 16384 + (1 * 64 + lane) * 16);
        frag_ab A1v = *(const frag_ab*)((char*)slab + p * 16384 + (9 * 64 + lane) * 16);
        acc[0][0] = mfma16(A0, w_r1, acc[0][0]); acc[0][1] = mfma16(A1v, w_r1, acc[0][1]);
        acc[1][0] = mfma16(A0, w_z1, acc[1][0]); acc[1][1] = mfma16(A1v, w_z1, acc[1][1]);
        acc[2][0] = mfma16(A0, w_n1, acc[2][0]); acc[2][1] = mfma16(A1v, w_n1, acc[2][1]);
      }
      if (hasst) *(uint4v*)((char*)slab + pn * 16384 + tid * 16) = stg;  // stg retired js3
      #pragma unroll
      for (int ga = 0; ga < 3; ++ga) {
        const float bb = (ga == 0) ? bri : (ga == 1) ? bzi : bni;
        const int col = ga * 256 + c;
        #pragma unroll
        for (int mt = 0; mt < 2; ++mt) {
          uint2v u;
          u[0] = (uint32_t)f2bf(acc[ga][mt][0] + bb) |
                 ((uint32_t)f2bf(acc[ga][mt][1] + bb) << 16);
          u[1] = (uint32_t)f2bf(acc[ga][mt][2] + bb) |
                 ((uint32_t)f2bf(acc[ga][mt][3] + bb) << 16);
          SCSTORE2(XGSLOT(t, g) + XGOFFS(col, (mt * 16 + q * 4) * 2), u);
        }
      }
      // poll-overlap (R9): polls ride the export drain.
      if (tid == 0) {
        if (t <= 125) POLL(CNTA(g), t + 3);
        POLL(CNTC(g), t - 3);
      }
      asm volatile("s_waitcnt vmcnt(0)" ::: "memory");
      BARRIER();
      if (tid == 0) PUBLISH(CNTB(g), t + 1);
      // trailing barrier removed (R10)
    }

  } else {
    // ------- Stage C: h2 recurrence (W_hh1) + gates + FC (R10 verbatim) ---
    const int g = bid - 128, row0 = g * 32;
    unsigned short* xg = (unsigned short*)smem;                       // 48 KB
    unsigned short (*h2b)[264] = (unsigned short (*)[264])(smem + 49152);
    for (int i = tid; i < 2 * 32 * 264; i += 1024)
      ((unsigned short*)(smem + 49152))[i] = 0;
    const int c = wave * 16 + c16;
    const float brh = bhh1[c], bzh = bhh1[HID + c], bnh = bhh1[2 * HID + c];
    const uint32_t bCr = (uint32_t)((L0_FRAGS + wave * KT1 + 8) << 10);
    const uint32_t bCz = (uint32_t)((L0_FRAGS + (16 + wave) * KT1 + 8) << 10);
    const uint32_t bCn = (uint32_t)((L0_FRAGS + (32 + wave) * KT1 + 8) << 10);
    frag_ab rr_[4], rz_[4], rn_[4];
    float h2m[2][4] = {{0, 0, 0, 0}, {0, 0, 0, 0}};
    #pragma unroll
    for (int i = 0; i < 4; ++i)
      ISSUE3(i, bCr + i * 1024 + lane16, bCz + i * 1024 + lane16,
                bCn + i * 1024 + lane16);

    if (tid == 0) POLL(CNTB(g), 1);
    BARRIER();
    { uint4v u0, u1, u2;
      SCLOAD4(u0, XGSLOT(0, g) + tid * 16);
      SCLOAD4(u1, XGSLOT(0, g) + 16384 + tid * 16);
      SCLOAD4(u2, XGSLOT(0, g) + 32768 + tid * 16);
      asm volatile("s_waitcnt vmcnt(0)" : "+v"(u0), "+v"(u1), "+v"(u2) :: "memory");
      *(uint4v*)((char*)xg + tid * 16) = u0;
      *(uint4v*)((char*)xg + 16384 + tid * 16) = u1;
      *(uint4v*)((char*)xg + 32768 + tid * 16) = u2; }
    if (tid == 0) POLL(CNTB(g), 2);
    __syncthreads();

    for (int t = 0; t < T_STEPS; ++t) {
      const int p = t & 1, pn = p ^ 1;
      uint4v s0 = {0,0,0,0}, s1 = {0,0,0,0}, s2 = {0,0,0,0};
      const bool hasst = (t + 1 < T_STEPS);
      if (hasst) {
        SCLOAD4(s0, XGSLOT(t + 1, g) + tid * 16);
        SCLOAD4(s1, XGSLOT(t + 1, g) + 16384 + tid * 16);
        SCLOAD4(s2, XGSLOT(t + 1, g) + 32768 + tid * 16);
      }
      f32x4 acc[3][2];
      #pragma unroll
      for (int ga = 0; ga < 3; ++ga) { acc[ga][0] = (f32x4){0,0,0,0};
                                       acc[ga][1] = (f32x4){0,0,0,0}; }
      #pragma unroll
      for (int i = 0; i < 8; ++i) {
        const int sl = i & 3;
        WAIT3(sl, "9");
        frag_ab A0  = *(const frag_ab*)&h2b[p * 32 + c16][i * 32 + q * 8];
        frag_ab A1v = *(const frag_ab*)&h2b[p * 32 + 16 + c16][i * 32 + q * 8];
        acc[0][0] = mfma16(A0, rr_[sl], acc[0][0]); acc[0][1] = mfma16(A1v, rr_[sl], acc[0][1]);
        acc[1][0] = mfma16(A0, rz_[sl], acc[1][0]); acc[1][1] = mfma16(A1v, rz_[sl], acc[1][1]);
        acc[2][0] = mfma16(A0, rn_[sl], acc[2][0]); acc[2][1] = mfma16(A1v, rn_[sl], acc[2][1]);
        const int nk = (i + 4) & 7;
        ISSUE3(sl, bCr + nk * 1024 + lane16, bCz + nk * 1024 + lane16,
                   bCn + nk * 1024 + lane16);
      }
      // epilogue: read xg(t) from LDS (swizzled), gates, h2 update
      #pragma unroll
      for (int mt = 0; mt < 2; ++mt) {
        uint2v ur = *(const uint2v*)((char*)xg + XGOFFS(0 * 256 + c, (mt * 16 + q * 4) * 2));
        uint2v uz = *(const uint2v*)((char*)xg + XGOFFS(1 * 256 + c, (mt * 16 + q * 4) * 2));
        uint2v un = *(const uint2v*)((char*)xg + XGOFFS(2 * 256 + c, (mt * 16 + q * 4) * 2));
        #pragma unroll
        for (int rrI = 0; rrI < 4; ++rrI) {
          const int row = mt * 16 + q * 4 + rrI;
          const uint32_t wr = (rrI < 2) ? ur[0] : ur[1];
          const uint32_t wz = (rrI < 2) ? uz[0] : uz[1];
          const uint32_t wn = (rrI < 2) ? un[0] : un[1];
          const int sh = (rrI & 1) * 16;
          float xr = bf2f((unsigned short)(wr >> sh));
          float xz = bf2f((unsigned short)(wz >> sh));
          float xn = bf2f((unsigned short)(wn >> sh));
          float rg = sigmoidf_(xr + acc[0][mt][rrI] + brh);
          float zg = sigmoidf_(xz + acc[1][mt][rrI] + bzh);
          float ng = tanhf_(xn + rg * (acc[2][mt][rrI] + bnh));
          float hn = (1.f - zg) * ng + zg * h2m[mt][rrI];
          h2m[mt][rrI] = hn;
          h2b[pn * 32 + row][c] = f2bf(hn);
        }
      }
      BARRIER();   // all xg(t) reads done before overwrite
      // poll-overlap (R9): tid0's poll rides the staging drains.
      if (tid == 0 && t <= 125) POLL(CNTB(g), t + 3);
      if (hasst) {
        asm volatile("s_waitcnt vmcnt(0)" : "+v"(s0), "+v"(s1), "+v"(s2) :: "memory");
        *(uint4v*)((char*)xg + tid * 16) = s0;
        *(uint4v*)((char*)xg + 16384 + tid * 16) = s1;
        *(uint4v*)((char*)xg + 32768 + tid * 16) = s2;
      }
      BARRIER();
      if (tid == 0) PUBLISH(CNTC(g), t + 1);
      // trailing barrier removed (R10)
    }

    // FC head from h2b parity 0 (h2(127): pn of t=127 is 0)
    if (tid < 128) {
      const int row = tid >> 2, o = tid & 3;
      float acc2 = fcb[o];
      #pragma unroll 8
      for (int k = 0; k < HID; ++k)
        acc2 += bf2f(h2b[row][k]) * fcw[o * HID + k];
      float sg = sigmoidf_(acc2);
      out[(size_t)(row0 + row) * 4 + o] = sg * 2.f - 1.f;
    }
  }
#undef BARRIER
#undef ISSUE3
#undef WAIT3
#undef RESLOAD
#undef SCLOAD4
#undef SCSTORE4
#undef SCSTORE2
#undef PUBLISH
#undef POLL
}

extern "C" void kernel_launch(void* const* d_in, const int* in_sizes, int n_in,
                              void* d_out, int out_size, void* d_ws, size_t ws_size,
                              hipStream_t stream) {
  const float* x    = (const float*)d_in[0];
  const float* Wih0 = (const float*)d_in[1];
  const float* Whh0 = (const float*)d_in[2];
  const float* bih0 = (const float*)d_in[3];
  const float* bhh0 = (const float*)d_in[4];
  const float* Wih1 = (const float*)d_in[5];
  const float* Whh1 = (const float*)d_in[6];
  const float* bih1 = (const float*)d_in[7];
  const float* bhh1 = (const float*)d_in[8];
  const float* fcw  = (const float*)d_in[9];
  const float* fcb  = (const float*)d_in[10];

  unsigned short* wq = (unsigned short*)d_ws;
  uint32_t* cnt = (uint32_t*)((char*)d_ws + CNT_OFF);

  repack_w<<<(TOT_FRAGS * 64 + 255) / 256, 256, 0, stream>>>(Wih0, Whh0, Wih1, Whh1, wq);
  clear_cnt<<<12, 256, 0, stream>>>(cnt);
  gru_pipe<<<192, 1024, 0, stream>>>(x, bih0, bhh0, bih1, bhh1, fcw, fcb,
                                     (char*)d_ws, (float*)d_out);
}